// Round 7
// baseline (1161.205 us; speedup 1.0000x reference)
//
#include <hip/hip_runtime.h>

#define HID 128
#define SCAN_CHUNK 1024
#define POOL_CHUNK 512

// binned CSR build params
#define NB 256
#define BW 400
#define DEPTH 24
#define CH 2048

typedef __attribute__((ext_vector_type(8))) short bf16x8;
typedef __attribute__((ext_vector_type(4))) float f32x4;

// ---------------- bf16 helpers (RNE pack, shift unpack) ----------------
__device__ inline float blo(unsigned u) { return __uint_as_float(u << 16); }
__device__ inline float bhi(unsigned u) { return __uint_as_float(u & 0xffff0000u); }
__device__ inline unsigned rne16(float x) {
  unsigned u = __float_as_uint(x);
  return (u + 0x7fffu + ((u >> 16) & 1u)) >> 16;
}
__device__ inline unsigned pk2(float a, float b) { return (rne16(b) << 16) | rne16(a); }

// ---------------- utility: fill int buffers ----------------
__global__ void k_fill32(int* __restrict__ p, int n, int val) {
  int i = blockIdx.x * blockDim.x + threadIdx.x;
  int stride = gridDim.x * blockDim.x;
  for (; i < n; i += stride) p[i] = val;
}

// ---------------- weight transpose + bf16 pack: Wt[c][k] from W[k][c] ----------
__global__ void k_prep_w(const float* __restrict__ W, unsigned* __restrict__ Wt,
                         int K, int KP2) {
  int idx = blockIdx.x * 256 + threadIdx.x;
  int total = 128 * KP2;
  if (idx >= total) return;
  int c = idx / KP2, kk = idx - c * KP2;
  int k0 = kk * 2, k1 = k0 + 1;
  float v0 = (k0 < K) ? W[(long)k0 * 128 + c] : 0.f;
  float v1 = (k1 < K) ? W[(long)k1 * 128 + c] : 0.f;
  Wt[idx] = pk2(v0, v1);
}

// ---------------- bucket histogram (LDS-staged) ----------------
__global__ __launch_bounds__(256) void k_hist(const int* __restrict__ dst, int E, int N,
                                              int* __restrict__ bhist) {
  __shared__ int h[NB];
  int t = threadIdx.x;
  h[t] = 0;
  __syncthreads();
  int i = blockIdx.x * blockDim.x + t;
  int stride = gridDim.x * blockDim.x;
  for (; i < E; i += stride) {
    int b = (int)(((long long)dst[i] * NB) / N);
    atomicAdd(&h[b], 1);
  }
  __syncthreads();
  if (h[t]) atomicAdd(&bhist[t], h[t]);
}

__global__ void k_bscan(const int* __restrict__ bhist, int* __restrict__ bstart,
                        int* __restrict__ gcur, int E) {
  if (blockIdx.x == 0 && threadIdx.x == 0) {
    int run = 0;
    for (int b = 0; b < NB; ++b) { bstart[b] = run; gcur[b] = run; run += bhist[b]; }
    bstart[NB] = run; // == E
  }
}

// ---------------- LDS-staged scatter into bucket-major order ----------------
__global__ __launch_bounds__(256) void k_scatter(const int* __restrict__ src,
                                                 const int* __restrict__ dst,
                                                 int E, int N,
                                                 unsigned long long* __restrict__ binned,
                                                 int* __restrict__ gcur) {
  __shared__ unsigned long long buf[NB][DEPTH]; // 48 KB
  __shared__ int cnt[NB];
  int t = threadIdx.x;
  long cover = (long)gridDim.x * CH;
  int nround = (int)((E + cover - 1) / cover);
  for (int r = 0; r < nround; ++r) {
    cnt[t] = 0;
    __syncthreads();
    long base = (long)r * cover + (long)blockIdx.x * CH;
#pragma unroll
    for (int k = 0; k < CH / 256; ++k) {
      long i = base + k * 256 + t;
      if (i < E) {
        int s = src[i], d = dst[i];
        int b = (int)(((long long)d * NB) / N);
        unsigned long long pack =
            ((unsigned long long)(unsigned)d << 32) | (unsigned)s;
        int slot = atomicAdd(&cnt[b], 1);
        if (slot < DEPTH) buf[b][slot] = pack;
        else { int g = atomicAdd(&gcur[b], 1); binned[g] = pack; } // rare spill
      }
    }
    __syncthreads();
    {
      int c = cnt[t];
      if (c > DEPTH) c = DEPTH;
      if (c > 0) {
        int g = atomicAdd(&gcur[t], c);
        for (int k = 0; k < c; ++k) binned[g + k] = buf[t][k];
      }
    }
    __syncthreads();
  }
}

// ---------------- per-bucket degree histogram ----------------
__global__ __launch_bounds__(256) void k_bdeg(const unsigned long long* __restrict__ binned,
                                              const int* __restrict__ bstart, int N,
                                              int* __restrict__ deg) {
  __shared__ int hist[BW];
  int b = blockIdx.x;
  int t = threadIdx.x;
  int d0 = (int)(((long long)b * N + NB - 1) / NB);
  int d1 = (int)(((long long)(b + 1) * N + NB - 1) / NB);
  if (d1 > N) d1 = N;
  int W = d1 - d0;
  for (int w = t; w < W; w += 256) hist[w] = 0;
  __syncthreads();
  int s = bstart[b], e = bstart[b + 1];
  for (int i = s + t; i < e; i += 256) {
    int d = (int)(binned[i] >> 32);
    atomicAdd(&hist[d - d0], 1);
  }
  __syncthreads();
  for (int w = t; w < W; w += 256) deg[d0 + w] = hist[w];
}

__global__ void k_dinv(const int* __restrict__ deg, float* __restrict__ dinv, int N) {
  int i = blockIdx.x * blockDim.x + threadIdx.x;
  int stride = gridDim.x * blockDim.x;
  for (; i < N; i += stride) dinv[i] = rsqrtf((float)(deg[i] + 1)); // +1 = self loop
}

// ---------------- exclusive scan of deg -> rowstart ----------------
__global__ void k_scan_block_sums(const int* __restrict__ deg, int N, int* __restrict__ bsum) {
  __shared__ int sh[256];
  int base = blockIdx.x * SCAN_CHUNK;
  int t = threadIdx.x;
  int s = 0;
#pragma unroll
  for (int j = 0; j < 4; ++j) {
    int idx = base + t * 4 + j;
    if (idx < N) s += deg[idx];
  }
  sh[t] = s;
  __syncthreads();
  for (int off = 128; off > 0; off >>= 1) {
    if (t < off) sh[t] += sh[t + off];
    __syncthreads();
  }
  if (t == 0) bsum[blockIdx.x] = sh[0];
}

__global__ void k_scan_offsets(const int* __restrict__ bsum, int nb, int* __restrict__ boff) {
  if (blockIdx.x == 0 && threadIdx.x == 0) {
    int run = 0;
    for (int i = 0; i < nb; ++i) { boff[i] = run; run += bsum[i]; }
  }
}

__global__ void k_scan_write(const int* __restrict__ deg, int N,
                             const int* __restrict__ boff, int* __restrict__ rowstart) {
  __shared__ int sh[256];
  int base = blockIdx.x * SCAN_CHUNK;
  int t = threadIdx.x;
  int v[4];
  int s = 0;
#pragma unroll
  for (int j = 0; j < 4; ++j) {
    int idx = base + t * 4 + j;
    v[j] = (idx < N) ? deg[idx] : 0;
    s += v[j];
  }
  sh[t] = s;
  __syncthreads();
  for (int off = 1; off < 256; off <<= 1) {
    int x = 0;
    if (t >= off) x = sh[t - off];
    __syncthreads();
    sh[t] += x;
    __syncthreads();
  }
  int excl = sh[t] - s;
  int run = boff[blockIdx.x] + excl;
#pragma unroll
  for (int j = 0; j < 4; ++j) {
    int idx = base + t * 4 + j;
    if (idx < N) rowstart[idx] = run;
    run += v[j];
  }
}

// ---------------- per-bucket CSR placement with LDS cursors ----------------
__global__ __launch_bounds__(256) void k_place(const unsigned long long* __restrict__ binned,
                                               const int* __restrict__ bstart,
                                               const int* __restrict__ rowstart, int N,
                                               int* __restrict__ csr) {
  __shared__ int cur[BW];
  int b = blockIdx.x;
  int t = threadIdx.x;
  int d0 = (int)(((long long)b * N + NB - 1) / NB);
  int d1 = (int)(((long long)(b + 1) * N + NB - 1) / NB);
  if (d1 > N) d1 = N;
  int W = d1 - d0;
  for (int w = t; w < W; w += 256) cur[w] = 0;
  __syncthreads();
  int s = bstart[b], e = bstart[b + 1];
  for (int i = s + t; i < e; i += 256) {
    unsigned long long p = binned[i];
    int d = (int)(p >> 32);
    int sn = (int)(p & 0xffffffffu);
    int pos = rowstart[d] + atomicAdd(&cur[d - d0], 1);
    csr[pos] = sn;
  }
}

// ============ MFMA GEMM layers 2/3, LDS-resident A+B (swizzled granules) =========
// Block 256 (4 waves) computes 128 rows x 128 cols. A from half-tables (bf16).
// LDS: A tile [128 rows][16 granules16B] + B tile [128 cols][16 granules16B] = 64KB.
// Granule swizzle: slot q holds logical k-granule (q ^ (row&15)).
__global__ __launch_bounds__(256) void k_gemm_mf2(const unsigned* __restrict__ A0,
                                                  const unsigned* __restrict__ A1,
                                                  const unsigned* __restrict__ Wt,
                                                  const float* __restrict__ dscale,
                                                  unsigned* __restrict__ C0,
                                                  unsigned* __restrict__ C1, int N) {
  __shared__ uint4 lds[4096];  // [0,2048): A, [2048,4096): B
  int t = threadIdx.x;
  int w = t >> 6, l = t & 63;
  int lr = l & 15, kg = l >> 4;
  int blk0 = blockIdx.x * 128;

  // ---- stage A (swizzled source granule, linear LDS) ----
#pragma unroll
  for (int it = 0; it < 8; ++it) {
    int g = it * 256 + t;
    int row = g >> 4, q = g & 15;
    int kq = q ^ (row & 15);
    int rg = blk0 + row;
    uint4 v = make_uint4(0u, 0u, 0u, 0u);
    if (rg < N)
      v = (kq < 8) ? *(const uint4*)&A0[(long)rg * 32 + kq * 4]
                   : *(const uint4*)&A1[(long)rg * 32 + (kq - 8) * 4];
    lds[g] = v;
  }
  // ---- stage B ----
#pragma unroll
  for (int it = 0; it < 8; ++it) {
    int g = it * 256 + t;
    int c = g >> 4, q = g & 15;
    int kq = q ^ (c & 15);
    lds[2048 + g] = *(const uint4*)&Wt[c * 64 + kq * 4];
  }
  __syncthreads();

  f32x4 acc[2][8];
#pragma unroll
  for (int rt = 0; rt < 2; ++rt)
#pragma unroll
    for (int f = 0; f < 8; ++f) acc[rt][f] = (f32x4){0.f, 0.f, 0.f, 0.f};

  int rl0 = w * 32 + lr, rl1 = w * 32 + 16 + lr;
#pragma unroll
  for (int kt = 0; kt < 4; ++kt) {
    int kq = kt * 4 + kg;
    union { uint4 u; bf16x8 b; } a0, a1;
    a0.u = lds[rl0 * 16 + (kq ^ lr)];
    a1.u = lds[rl1 * 16 + (kq ^ lr)];
#pragma unroll
    for (int f = 0; f < 8; ++f) {
      union { uint4 u; bf16x8 b; } bb;
      bb.u = lds[2048 + (f * 16 + lr) * 16 + (kq ^ lr)];
      acc[0][f] = __builtin_amdgcn_mfma_f32_16x16x32_bf16(a0.b, bb.b, acc[0][f], 0, 0, 0);
      acc[1][f] = __builtin_amdgcn_mfma_f32_16x16x32_bf16(a1.b, bb.b, acc[1][f], 0, 0, 0);
    }
  }
#pragma unroll
  for (int rt = 0; rt < 2; ++rt) {
#pragma unroll
    for (int reg = 0; reg < 4; ++reg) {
      int row = blk0 + w * 32 + rt * 16 + kg * 4 + reg;
      float ds = (row < N) ? dscale[row] : 0.f;
#pragma unroll
      for (int f = 0; f < 8; ++f) {
        float v = acc[rt][f][reg] * ds;
        float pv = __shfl_xor(v, 1);
        if (!(l & 1) && row < N) {
          int cu = f * 8 + (lr >> 1);           // global u32 col 0..63
          unsigned* dstp = (f >= 4) ? C1 : C0;
          dstp[(long)row * 32 + (cu & 31)] = pk2(v, pv);
        }
      }
    }
  }
}

// ============ MFMA GEMM layer 1: x f32 -> bf16 in-flight; C to halves ============
__global__ __launch_bounds__(256) void k_gemm1_mf(const float* __restrict__ X,
                                                  const unsigned* __restrict__ Wt,
                                                  const float* __restrict__ dscale,
                                                  unsigned* __restrict__ C0,
                                                  unsigned* __restrict__ C1,
                                                  int N, int K) {
  int t = threadIdx.x;
  int w = t >> 6;
  int l = t & 63;
  int lr = l & 15;
  int kg = l >> 4;
  int wr0 = blockIdx.x * 128 + w * 32;

  f32x4 acc[2][8];
#pragma unroll
  for (int rt = 0; rt < 2; ++rt)
#pragma unroll
    for (int f = 0; f < 8; ++f) acc[rt][f] = (f32x4){0.f, 0.f, 0.f, 0.f};

  int r0 = wr0 + lr, r1 = wr0 + 16 + lr;
  int nkt = (K + 31) / 32;  // 9 for K=260
  for (int kt = 0; kt < nkt; ++kt) {
    int kb = kt * 32 + kg * 8;
    bf16x8 a0 = {}, a1 = {};
    if (kb + 7 < K) {
      if (r0 < N) {
        const float* p = &X[(long)r0 * K + kb];
        float4 u = *(const float4*)p, v = *(const float4*)(p + 4);
        union { uint4 q; bf16x8 b; } cv;
        cv.q.x = pk2(u.x, u.y); cv.q.y = pk2(u.z, u.w);
        cv.q.z = pk2(v.x, v.y); cv.q.w = pk2(v.z, v.w);
        a0 = cv.b;
      }
      if (r1 < N) {
        const float* p = &X[(long)r1 * K + kb];
        float4 u = *(const float4*)p, v = *(const float4*)(p + 4);
        union { uint4 q; bf16x8 b; } cv;
        cv.q.x = pk2(u.x, u.y); cv.q.y = pk2(u.z, u.w);
        cv.q.z = pk2(v.x, v.y); cv.q.w = pk2(v.z, v.w);
        a1 = cv.b;
      }
    } else if (kb < K) {  // partial tail
      float t0[8], t1[8];
#pragma unroll
      for (int j = 0; j < 8; ++j) {
        int k = kb + j;
        t0[j] = (r0 < N && k < K) ? X[(long)r0 * K + k] : 0.f;
        t1[j] = (r1 < N && k < K) ? X[(long)r1 * K + k] : 0.f;
      }
      union { uint4 q; bf16x8 b; } c0, c1;
      c0.q.x = pk2(t0[0], t0[1]); c0.q.y = pk2(t0[2], t0[3]);
      c0.q.z = pk2(t0[4], t0[5]); c0.q.w = pk2(t0[6], t0[7]);
      c1.q.x = pk2(t1[0], t1[1]); c1.q.y = pk2(t1[2], t1[3]);
      c1.q.z = pk2(t1[4], t1[5]); c1.q.w = pk2(t1[6], t1[7]);
      a0 = c0.b; a1 = c1.b;
    }
    int ko = kt * 16 + kg * 4;
#pragma unroll
    for (int f = 0; f < 8; ++f) {
      bf16x8 b = *(const bf16x8*)&Wt[(f * 16 + lr) * 144 + ko];
      acc[0][f] = __builtin_amdgcn_mfma_f32_16x16x32_bf16(a0, b, acc[0][f], 0, 0, 0);
      acc[1][f] = __builtin_amdgcn_mfma_f32_16x16x32_bf16(a1, b, acc[1][f], 0, 0, 0);
    }
  }
#pragma unroll
  for (int rt = 0; rt < 2; ++rt) {
#pragma unroll
    for (int reg = 0; reg < 4; ++reg) {
      int row = wr0 + rt * 16 + kg * 4 + reg;
      float ds = (row < N) ? dscale[row] : 0.f;
#pragma unroll
      for (int f = 0; f < 8; ++f) {
        float v = acc[rt][f][reg] * ds;
        float pv = __shfl_xor(v, 1);
        if (!(l & 1) && row < N) {
          int cu = f * 8 + (lr >> 1);
          unsigned* dstp = (f >= 4) ? C1 : C0;
          dstp[(long)row * 32 + (cu & 31)] = pk2(v, pv);
        }
      }
    }
  }
}

// ---------------- pull aggregation over a 64-channel half-table ----------------
// T: u32 [N][32] (one half, pre-scaled by dinv). out: u32 [N][32].
// out[i][hc] = relu( dinv[i]*(T[i][hc] + sum_nbr T[s][hc]) + bias64[hc] )
__global__ __launch_bounds__(256) void k_agg_h(const unsigned* __restrict__ T,
                                               const float* __restrict__ dinv,
                                               const int* __restrict__ rowstart,
                                               const int* __restrict__ deg,
                                               const int* __restrict__ csr,
                                               const float* __restrict__ bias64,
                                               unsigned* __restrict__ outu, int N) {
  __shared__ float sh[8][64];
  int i = blockIdx.x;
  int t = threadIdx.x;
  int g = t >> 5, lane = t & 31;

  float ax = 0.f, ay = 0.f;
  if (g == 0) {
    unsigned u = T[(long)i * 32 + lane];  // self-loop term (pre-scaled)
    ax = blo(u); ay = bhi(u);
  }
  int s0 = rowstart[i];
  int d = deg[i];
  int j = g;
  for (; j + 8 < d; j += 16) {
    unsigned u1 = T[(long)csr[s0 + j] * 32 + lane];
    unsigned u2 = T[(long)csr[s0 + j + 8] * 32 + lane];
    ax += blo(u1) + blo(u2);
    ay += bhi(u1) + bhi(u2);
  }
  if (j < d) {
    unsigned u1 = T[(long)csr[s0 + j] * 32 + lane];
    ax += blo(u1); ay += bhi(u1);
  }
  sh[g][lane * 2] = ax;
  sh[g][lane * 2 + 1] = ay;
  __syncthreads();
  if (t < 32) {
    float t0 = 0.f, t1 = 0.f;
#pragma unroll
    for (int gg = 0; gg < 8; ++gg) { t0 += sh[gg][t * 2]; t1 += sh[gg][t * 2 + 1]; }
    float di = dinv[i];
    float v0 = fmaxf(di * t0 + bias64[t * 2], 0.f);
    float v1 = fmaxf(di * t1 + bias64[t * 2 + 1], 0.f);
    outu[(long)i * 32 + t] = pk2(v0, v1);
  }
}

// ---------------- graph start offsets from sorted batch ----------------
__global__ void k_starts(const int* __restrict__ batch, int N, int* __restrict__ start) {
  int i = blockIdx.x * blockDim.x + threadIdx.x;
  int stride = gridDim.x * blockDim.x;
  for (; i < N; i += stride) {
    int g = batch[i];
    if (i == 0) {
      start[g] = 0;
    } else if (batch[i - 1] != g) {
      start[g] = i;
    }
  }
}

__global__ void k_fix_starts(int* __restrict__ start, int G, int N) {
  if (blockIdx.x == 0 && threadIdx.x == 0) {
    start[G] = N;
    for (int g = G - 1; g >= 0; --g)
      if (start[g] < 0) start[g] = start[g + 1];
  }
}

// ---------------- mean-pool partial sums (batch sorted, bf16 halves) ------------
__global__ __launch_bounds__(128) void k_pool(const unsigned* __restrict__ H0,
                                              const unsigned* __restrict__ H1,
                                              const int* __restrict__ batch,
                                              float* __restrict__ psum, int N) {
  __shared__ int bsh[POOL_CHUNK];
  int c = threadIdx.x;
  int start = blockIdx.x * POOL_CHUNK;
  int end = min(N, start + POOL_CHUNK);
  int len = end - start;
  if (len <= 0) return;
  for (int i = c; i < len; i += 128) bsh[i] = batch[start + i];
  __syncthreads();
  int cur = bsh[0];
  float acc = 0.f;
  const unsigned* H = (c >= 64) ? H1 : H0;
  int cl = c & 63;
  int half = cl >> 1;
  int odd = cl & 1;
  for (int i = 0; i < len; ++i) {
    int g = bsh[i];
    if (g != cur) {
      atomicAdd(&psum[cur * HID + c], acc);
      acc = 0.f;
      cur = g;
    }
    unsigned u = H[(long)(start + i) * 32 + half];
    acc += odd ? bhi(u) : blo(u);
  }
  atomicAdd(&psum[cur * HID + c], acc);
}

// ---------------- MLP head ----------------
__global__ __launch_bounds__(128) void k_head(const float* __restrict__ psum,
                                              const int* __restrict__ gstart,
                                              const float* __restrict__ fc1w,
                                              const float* __restrict__ fc1b,
                                              const float* __restrict__ fc2w,
                                              const float* __restrict__ fc2b,
                                              float* __restrict__ out, int G) {
  __shared__ float pooled[HID];
  __shared__ float z1[HID];
  int g = blockIdx.x;
  int c = threadIdx.x;
  float cn = fmaxf((float)(gstart[g + 1] - gstart[g]), 1.f);
  pooled[c] = psum[g * HID + c] / cn;
  __syncthreads();
  float a = fc1b[c];
#pragma unroll 8
  for (int k = 0; k < HID; ++k) a += pooled[k] * fc1w[k * HID + c];
  z1[c] = fmaxf(a, 0.f);
  __syncthreads();
  if (c < 16) {
    float o = fc2b[c];
#pragma unroll 8
    for (int k = 0; k < HID; ++k) o += z1[k] * fc2w[k * 16 + c];
    out[g * 16 + c] = o;
  }
}

extern "C" void kernel_launch(void* const* d_in, const int* in_sizes, int n_in,
                              void* d_out, int out_size, void* d_ws, size_t ws_size,
                              hipStream_t stream) {
  const float* x     = (const float*)d_in[0];
  const int*   ei    = (const int*)d_in[1];
  const int*   batch = (const int*)d_in[2];
  const float* w1    = (const float*)d_in[3];
  const float* b1    = (const float*)d_in[4];
  const float* w2    = (const float*)d_in[5];
  const float* b2    = (const float*)d_in[6];
  const float* w3    = (const float*)d_in[7];
  const float* b3    = (const float*)d_in[8];
  const float* fc1w  = (const float*)d_in[9];
  const float* fc1b  = (const float*)d_in[10];
  const float* fc2w  = (const float*)d_in[11];
  const float* fc2b  = (const float*)d_in[12];
  float* out = (float*)d_out;

  const int IN = in_sizes[3] / HID;   // 260
  const int N  = in_sizes[0] / IN;    // 100000
  const int E  = in_sizes[1] / 2;     // 3200000
  const int G  = out_size / 16;       // 64

  const int* srcp = ei;
  const int* dstp = ei + E;

  // ---- workspace carve ----
  char* wsp = (char*)d_ws;
  auto alloc = [&](size_t bytes) {
    char* p = wsp;
    wsp += (bytes + 255) & ~(size_t)255;
    return p;
  };
  int*   deg      = (int*)alloc((size_t)N * 4);
  int*   rowstart = (int*)alloc((size_t)N * 4);
  int*   bsum     = (int*)alloc(1024 * 4);
  int*   boff     = (int*)alloc(1024 * 4);
  int*   bhist    = (int*)alloc(NB * 4);
  int*   bstart   = (int*)alloc((NB + 1) * 4);
  int*   gcur     = (int*)alloc(NB * 4);
  int*   gstart   = (int*)alloc((size_t)(G + 1) * 4);
  float* dinv     = (float*)alloc((size_t)N * 4);
  float* psum     = (float*)alloc((size_t)G * HID * 4);
  unsigned* Wt1   = (unsigned*)alloc(128 * 144 * 4);
  unsigned* Wt2   = (unsigned*)alloc(128 * 64 * 4);
  unsigned* Wt3   = (unsigned*)alloc(128 * 64 * 4);
  int*   csr      = (int*)alloc((size_t)E * 4);
  unsigned* A0    = (unsigned*)alloc((size_t)N * 32 * 4);  // bf16 half ch 0-63
  unsigned* A1    = (unsigned*)alloc((size_t)N * 32 * 4);  // bf16 half ch 64-127
  unsigned* B0    = (unsigned*)alloc((size_t)N * 32 * 4);
  unsigned* B1    = (unsigned*)alloc((size_t)N * 32 * 4);
  // binned edge array (E x 8B = 25.6MB) aliases A0|A1 (contiguous 25.6MB);
  // fully consumed by k_bdeg/k_place before gemm1 writes A halves.
  unsigned long long* binned = (unsigned long long*)A0;

  // ---- init ----
  k_fill32<<<4, 256, 0, stream>>>((int*)psum, G * HID, 0);
  k_fill32<<<1, 128, 0, stream>>>(gstart, G + 1, -1);
  k_fill32<<<1, 256, 0, stream>>>(bhist, NB, 0);

  // ---- weight prep (transpose + bf16) ----
  k_prep_w<<<72, 256, 0, stream>>>(w1, Wt1, IN, 144);
  k_prep_w<<<32, 256, 0, stream>>>(w2, Wt2, HID, 64);
  k_prep_w<<<32, 256, 0, stream>>>(w3, Wt3, HID, 64);

  // ---- binned CSR build ----
  k_hist<<<512, 256, 0, stream>>>(dstp, E, N, bhist);
  k_bscan<<<1, 1, 0, stream>>>(bhist, bstart, gcur, E);
  k_scatter<<<512, 256, 0, stream>>>(srcp, dstp, E, N, binned, gcur);
  k_bdeg<<<NB, 256, 0, stream>>>(binned, bstart, N, deg);
  k_dinv<<<(N + 255) / 256, 256, 0, stream>>>(deg, dinv, N);

  int nb = (N + SCAN_CHUNK - 1) / SCAN_CHUNK;
  k_scan_block_sums<<<nb, 256, 0, stream>>>(deg, N, bsum);
  k_scan_offsets<<<1, 1, 0, stream>>>(bsum, nb, boff);
  k_scan_write<<<nb, 256, 0, stream>>>(deg, N, boff, rowstart);
  k_place<<<NB, 256, 0, stream>>>(binned, bstart, rowstart, N, csr);

  // ---- graph boundaries ----
  k_starts<<<256, 256, 0, stream>>>(batch, N, gstart);
  k_fix_starts<<<1, 1, 0, stream>>>(gstart, G, N);

  // ---- 3 GCN layers ----
  int gblocks = (N + 127) / 128;
  k_gemm1_mf<<<gblocks, 256, 0, stream>>>(x, Wt1, dinv, A0, A1, N, IN);
  k_agg_h<<<N, 256, 0, stream>>>(A0, dinv, rowstart, deg, csr, b1,      B0, N);
  k_agg_h<<<N, 256, 0, stream>>>(A1, dinv, rowstart, deg, csr, b1 + 64, B1, N);

  k_gemm_mf2<<<gblocks, 256, 0, stream>>>(B0, B1, Wt2, dinv, A0, A1, N);
  k_agg_h<<<N, 256, 0, stream>>>(A0, dinv, rowstart, deg, csr, b2,      B0, N);
  k_agg_h<<<N, 256, 0, stream>>>(A1, dinv, rowstart, deg, csr, b2 + 64, B1, N);

  k_gemm_mf2<<<gblocks, 256, 0, stream>>>(B0, B1, Wt3, dinv, A0, A1, N);
  k_agg_h<<<N, 256, 0, stream>>>(A0, dinv, rowstart, deg, csr, b3,      B0, N);
  k_agg_h<<<N, 256, 0, stream>>>(A1, dinv, rowstart, deg, csr, b3 + 64, B1, N);

  // ---- pool + head ----
  int pblocks = (N + POOL_CHUNK - 1) / POOL_CHUNK;
  k_pool<<<pblocks, 128, 0, stream>>>(B0, B1, batch, psum, N);
  k_head<<<G, 128, 0, stream>>>(psum, gstart, fc1w, fc1b, fc2w, fc2b, out, G);
}

// Round 8
// 762.115 us; speedup vs baseline: 1.5237x; 1.5237x over previous
//
#include <hip/hip_runtime.h>

#define HID 128
#define SCAN_CHUNK 1024

// binned CSR build params
#define NB 256
#define BW 400
#define DEPTH 24
#define CH 2048

typedef __attribute__((ext_vector_type(8))) short bf16x8;
typedef __attribute__((ext_vector_type(4))) float f32x4;

// ---------------- bf16 helpers (RNE pack, shift unpack) ----------------
__device__ inline float blo(unsigned u) { return __uint_as_float(u << 16); }
__device__ inline float bhi(unsigned u) { return __uint_as_float(u & 0xffff0000u); }
__device__ inline unsigned rne16(float x) {
  unsigned u = __float_as_uint(x);
  return (u + 0x7fffu + ((u >> 16) & 1u)) >> 16;
}
__device__ inline unsigned pk2(float a, float b) { return (rne16(b) << 16) | rne16(a); }

// ---------------- utility: fill int buffers ----------------
__global__ void k_fill32(int* __restrict__ p, int n, int val) {
  int i = blockIdx.x * blockDim.x + threadIdx.x;
  int stride = gridDim.x * blockDim.x;
  for (; i < n; i += stride) p[i] = val;
}

// ---------------- weight transpose + bf16 pack: Wt[c][k] from W[k][c] ----------
__global__ void k_prep_w(const float* __restrict__ W, unsigned* __restrict__ Wt,
                         int K, int KP2) {
  int idx = blockIdx.x * 256 + threadIdx.x;
  int total = 128 * KP2;
  if (idx >= total) return;
  int c = idx / KP2, kk = idx - c * KP2;
  int k0 = kk * 2, k1 = k0 + 1;
  float v0 = (k0 < K) ? W[(long)k0 * 128 + c] : 0.f;
  float v1 = (k1 < K) ? W[(long)k1 * 128 + c] : 0.f;
  Wt[idx] = pk2(v0, v1);
}

// ---------------- bucket histogram (LDS-staged) ----------------
__global__ __launch_bounds__(256) void k_hist(const int* __restrict__ dst, int E, int N,
                                              int* __restrict__ bhist) {
  __shared__ int h[NB];
  int t = threadIdx.x;
  h[t] = 0;
  __syncthreads();
  int i = blockIdx.x * blockDim.x + t;
  int stride = gridDim.x * blockDim.x;
  for (; i < E; i += stride) {
    int b = (int)(((long long)dst[i] * NB) / N);
    atomicAdd(&h[b], 1);
  }
  __syncthreads();
  if (h[t]) atomicAdd(&bhist[t], h[t]);
}

__global__ void k_bscan(const int* __restrict__ bhist, int* __restrict__ bstart,
                        int* __restrict__ gcur, int E) {
  if (blockIdx.x == 0 && threadIdx.x == 0) {
    int run = 0;
    for (int b = 0; b < NB; ++b) { bstart[b] = run; gcur[b] = run; run += bhist[b]; }
    bstart[NB] = run; // == E
  }
}

// ---------------- LDS-staged scatter into bucket-major order ----------------
__global__ __launch_bounds__(256) void k_scatter(const int* __restrict__ src,
                                                 const int* __restrict__ dst,
                                                 int E, int N,
                                                 unsigned long long* __restrict__ binned,
                                                 int* __restrict__ gcur) {
  __shared__ unsigned long long buf[NB][DEPTH]; // 48 KB
  __shared__ int cnt[NB];
  int t = threadIdx.x;
  long cover = (long)gridDim.x * CH;
  int nround = (int)((E + cover - 1) / cover);
  for (int r = 0; r < nround; ++r) {
    cnt[t] = 0;
    __syncthreads();
    long base = (long)r * cover + (long)blockIdx.x * CH;
#pragma unroll
    for (int k = 0; k < CH / 256; ++k) {
      long i = base + k * 256 + t;
      if (i < E) {
        int s = src[i], d = dst[i];
        int b = (int)(((long long)d * NB) / N);
        unsigned long long pack =
            ((unsigned long long)(unsigned)d << 32) | (unsigned)s;
        int slot = atomicAdd(&cnt[b], 1);
        if (slot < DEPTH) buf[b][slot] = pack;
        else { int g = atomicAdd(&gcur[b], 1); binned[g] = pack; } // rare spill
      }
    }
    __syncthreads();
    {
      int c = cnt[t];
      if (c > DEPTH) c = DEPTH;
      if (c > 0) {
        int g = atomicAdd(&gcur[t], c);
        for (int k = 0; k < c; ++k) binned[g + k] = buf[t][k];
      }
    }
    __syncthreads();
  }
}

// ---------------- per-bucket degree histogram ----------------
__global__ __launch_bounds__(256) void k_bdeg(const unsigned long long* __restrict__ binned,
                                              const int* __restrict__ bstart, int N,
                                              int* __restrict__ deg) {
  __shared__ int hist[BW];
  int b = blockIdx.x;
  int t = threadIdx.x;
  int d0 = (int)(((long long)b * N + NB - 1) / NB);
  int d1 = (int)(((long long)(b + 1) * N + NB - 1) / NB);
  if (d1 > N) d1 = N;
  int W = d1 - d0;
  for (int w = t; w < W; w += 256) hist[w] = 0;
  __syncthreads();
  int s = bstart[b], e = bstart[b + 1];
  for (int i = s + t; i < e; i += 256) {
    int d = (int)(binned[i] >> 32);
    atomicAdd(&hist[d - d0], 1);
  }
  __syncthreads();
  for (int w = t; w < W; w += 256) deg[d0 + w] = hist[w];
}

__global__ void k_dinv(const int* __restrict__ deg, float* __restrict__ dinv, int N) {
  int i = blockIdx.x * blockDim.x + threadIdx.x;
  int stride = gridDim.x * blockDim.x;
  for (; i < N; i += stride) dinv[i] = rsqrtf((float)(deg[i] + 1)); // +1 = self loop
}

// ---------------- exclusive scan of deg -> rowstart ----------------
__global__ void k_scan_block_sums(const int* __restrict__ deg, int N, int* __restrict__ bsum) {
  __shared__ int sh[256];
  int base = blockIdx.x * SCAN_CHUNK;
  int t = threadIdx.x;
  int s = 0;
#pragma unroll
  for (int j = 0; j < 4; ++j) {
    int idx = base + t * 4 + j;
    if (idx < N) s += deg[idx];
  }
  sh[t] = s;
  __syncthreads();
  for (int off = 128; off > 0; off >>= 1) {
    if (t < off) sh[t] += sh[t + off];
    __syncthreads();
  }
  if (t == 0) bsum[blockIdx.x] = sh[0];
}

__global__ void k_scan_offsets(const int* __restrict__ bsum, int nb, int* __restrict__ boff) {
  if (blockIdx.x == 0 && threadIdx.x == 0) {
    int run = 0;
    for (int i = 0; i < nb; ++i) { boff[i] = run; run += bsum[i]; }
  }
}

__global__ void k_scan_write(const int* __restrict__ deg, int N,
                             const int* __restrict__ boff, int* __restrict__ rowstart) {
  __shared__ int sh[256];
  int base = blockIdx.x * SCAN_CHUNK;
  int t = threadIdx.x;
  int v[4];
  int s = 0;
#pragma unroll
  for (int j = 0; j < 4; ++j) {
    int idx = base + t * 4 + j;
    v[j] = (idx < N) ? deg[idx] : 0;
    s += v[j];
  }
  sh[t] = s;
  __syncthreads();
  for (int off = 1; off < 256; off <<= 1) {
    int x = 0;
    if (t >= off) x = sh[t - off];
    __syncthreads();
    sh[t] += x;
    __syncthreads();
  }
  int excl = sh[t] - s;
  int run = boff[blockIdx.x] + excl;
#pragma unroll
  for (int j = 0; j < 4; ++j) {
    int idx = base + t * 4 + j;
    if (idx < N) rowstart[idx] = run;
    run += v[j];
  }
}

// ---------------- per-bucket CSR placement with LDS cursors ----------------
__global__ __launch_bounds__(256) void k_place(const unsigned long long* __restrict__ binned,
                                               const int* __restrict__ bstart,
                                               const int* __restrict__ rowstart, int N,
                                               int* __restrict__ csr) {
  __shared__ int cur[BW];
  int b = blockIdx.x;
  int t = threadIdx.x;
  int d0 = (int)(((long long)b * N + NB - 1) / NB);
  int d1 = (int)(((long long)(b + 1) * N + NB - 1) / NB);
  if (d1 > N) d1 = N;
  int W = d1 - d0;
  for (int w = t; w < W; w += 256) cur[w] = 0;
  __syncthreads();
  int s = bstart[b], e = bstart[b + 1];
  for (int i = s + t; i < e; i += 256) {
    unsigned long long p = binned[i];
    int d = (int)(p >> 32);
    int sn = (int)(p & 0xffffffffu);
    int pos = rowstart[d] + atomicAdd(&cur[d - d0], 1);
    csr[pos] = sn;
  }
}

// ============ MFMA GEMM, layers 2/3: Cbf16 = dinv(row)*(Abf16[N][128] @ W[128][128]) ==
// No LDS. Block = 256 (4 waves); wave computes 32 rows x 128 cols.
__global__ __launch_bounds__(256) void k_gemm_mf(const unsigned* __restrict__ A,
                                                 const unsigned* __restrict__ Wt,
                                                 const float* __restrict__ dscale,
                                                 unsigned* __restrict__ Cu, int N) {
  int t = threadIdx.x;
  int w = t >> 6;
  int l = t & 63;
  int lr = l & 15;
  int kg = l >> 4;
  int wr0 = blockIdx.x * 128 + w * 32;

  f32x4 acc[2][8];
#pragma unroll
  for (int rt = 0; rt < 2; ++rt)
#pragma unroll
    for (int f = 0; f < 8; ++f) acc[rt][f] = (f32x4){0.f, 0.f, 0.f, 0.f};

  int r0 = wr0 + lr, r1 = wr0 + 16 + lr;
#pragma unroll
  for (int kt = 0; kt < 4; ++kt) {
    int ko = kt * 16 + kg * 4;
    bf16x8 a0 = {}, a1 = {};
    if (r0 < N) a0 = *(const bf16x8*)&A[(long)r0 * 64 + ko];
    if (r1 < N) a1 = *(const bf16x8*)&A[(long)r1 * 64 + ko];
#pragma unroll
    for (int f = 0; f < 8; ++f) {
      bf16x8 b = *(const bf16x8*)&Wt[(f * 16 + lr) * 64 + ko];
      acc[0][f] = __builtin_amdgcn_mfma_f32_16x16x32_bf16(a0, b, acc[0][f], 0, 0, 0);
      acc[1][f] = __builtin_amdgcn_mfma_f32_16x16x32_bf16(a1, b, acc[1][f], 0, 0, 0);
    }
  }
#pragma unroll
  for (int rt = 0; rt < 2; ++rt) {
#pragma unroll
    for (int reg = 0; reg < 4; ++reg) {
      int row = wr0 + rt * 16 + kg * 4 + reg;
      float ds = (row < N) ? dscale[row] : 0.f;
#pragma unroll
      for (int f = 0; f < 8; ++f) {
        float v = acc[rt][f][reg] * ds;
        float pv = __shfl_xor(v, 1);
        if (!(l & 1) && row < N)
          Cu[(long)row * 64 + ((f * 16 + lr) >> 1)] = pk2(v, pv);
      }
    }
  }
}

// ============ MFMA GEMM, layer 1: x f32 -> bf16 in-flight ============
__global__ __launch_bounds__(256) void k_gemm1_mf(const float* __restrict__ X,
                                                  const unsigned* __restrict__ Wt,
                                                  const float* __restrict__ dscale,
                                                  unsigned* __restrict__ Cu, int N, int K) {
  int t = threadIdx.x;
  int w = t >> 6;
  int l = t & 63;
  int lr = l & 15;
  int kg = l >> 4;
  int wr0 = blockIdx.x * 128 + w * 32;

  f32x4 acc[2][8];
#pragma unroll
  for (int rt = 0; rt < 2; ++rt)
#pragma unroll
    for (int f = 0; f < 8; ++f) acc[rt][f] = (f32x4){0.f, 0.f, 0.f, 0.f};

  int r0 = wr0 + lr, r1 = wr0 + 16 + lr;
  int nkt = (K + 31) / 32;  // 9 for K=260
  for (int kt = 0; kt < nkt; ++kt) {
    int kb = kt * 32 + kg * 8;
    bf16x8 a0 = {}, a1 = {};
    if (kb + 7 < K) {
      if (r0 < N) {
        const float* p = &X[(long)r0 * K + kb];
        float4 u = *(const float4*)p, v = *(const float4*)(p + 4);
        union { uint4 q; bf16x8 b; } cv;
        cv.q.x = pk2(u.x, u.y); cv.q.y = pk2(u.z, u.w);
        cv.q.z = pk2(v.x, v.y); cv.q.w = pk2(v.z, v.w);
        a0 = cv.b;
      }
      if (r1 < N) {
        const float* p = &X[(long)r1 * K + kb];
        float4 u = *(const float4*)p, v = *(const float4*)(p + 4);
        union { uint4 q; bf16x8 b; } cv;
        cv.q.x = pk2(u.x, u.y); cv.q.y = pk2(u.z, u.w);
        cv.q.z = pk2(v.x, v.y); cv.q.w = pk2(v.z, v.w);
        a1 = cv.b;
      }
    } else if (kb < K) {  // partial tail (k=256..259)
      float t0[8], t1[8];
#pragma unroll
      for (int j = 0; j < 8; ++j) {
        int k = kb + j;
        t0[j] = (r0 < N && k < K) ? X[(long)r0 * K + k] : 0.f;
        t1[j] = (r1 < N && k < K) ? X[(long)r1 * K + k] : 0.f;
      }
      union { uint4 q; bf16x8 b; } c0, c1;
      c0.q.x = pk2(t0[0], t0[1]); c0.q.y = pk2(t0[2], t0[3]);
      c0.q.z = pk2(t0[4], t0[5]); c0.q.w = pk2(t0[6], t0[7]);
      c1.q.x = pk2(t1[0], t1[1]); c1.q.y = pk2(t1[2], t1[3]);
      c1.q.z = pk2(t1[4], t1[5]); c1.q.w = pk2(t1[6], t1[7]);
      a0 = c0.b; a1 = c1.b;
    }
    int ko = kt * 16 + kg * 4;
#pragma unroll
    for (int f = 0; f < 8; ++f) {
      bf16x8 b = *(const bf16x8*)&Wt[(f * 16 + lr) * 144 + ko];
      acc[0][f] = __builtin_amdgcn_mfma_f32_16x16x32_bf16(a0, b, acc[0][f], 0, 0, 0);
      acc[1][f] = __builtin_amdgcn_mfma_f32_16x16x32_bf16(a1, b, acc[1][f], 0, 0, 0);
    }
  }
#pragma unroll
  for (int rt = 0; rt < 2; ++rt) {
#pragma unroll
    for (int reg = 0; reg < 4; ++reg) {
      int row = wr0 + rt * 16 + kg * 4 + reg;
      float ds = (row < N) ? dscale[row] : 0.f;
#pragma unroll
      for (int f = 0; f < 8; ++f) {
        float v = acc[rt][f][reg] * ds;
        float pv = __shfl_xor(v, 1);
        if (!(l & 1) && row < N)
          Cu[(long)row * 64 + ((f * 16 + lr) >> 1)] = pk2(v, pv);
      }
    }
  }
}

// ---------------- pull aggregation + bias + relu (bf16 rows) ----------------
__global__ __launch_bounds__(256) void k_agg(const uint2* __restrict__ T,   // [N][32]
                                             const float* __restrict__ dinv,
                                             const int* __restrict__ rowstart,
                                             const int* __restrict__ deg,
                                             const int* __restrict__ csr,
                                             const float* __restrict__ bias,
                                             unsigned* __restrict__ outu,   // [N][64]
                                             int N) {
  __shared__ float sh[8][128];
  int i = blockIdx.x;
  int t = threadIdx.x;
  int g = t >> 5;
  int lane = t & 31;

  float4 acc = make_float4(0.f, 0.f, 0.f, 0.f);
  if (g == 0) {
    uint2 u = T[(long)i * 32 + lane];  // self-loop (pre-scaled by dinv)
    acc.x = blo(u.x); acc.y = bhi(u.x); acc.z = blo(u.y); acc.w = bhi(u.y);
  }

  int s0 = rowstart[i];
  int d = deg[i];
  int j = g;
  for (; j + 8 < d; j += 16) {
    int s1 = csr[s0 + j];
    int s2 = csr[s0 + j + 8];
    uint2 u1 = T[(long)s1 * 32 + lane];
    uint2 u2 = T[(long)s2 * 32 + lane];
    acc.x += blo(u1.x) + blo(u2.x);
    acc.y += bhi(u1.x) + bhi(u2.x);
    acc.z += blo(u1.y) + blo(u2.y);
    acc.w += bhi(u1.y) + bhi(u2.y);
  }
  if (j < d) {
    int s1 = csr[s0 + j];
    uint2 u1 = T[(long)s1 * 32 + lane];
    acc.x += blo(u1.x); acc.y += bhi(u1.x); acc.z += blo(u1.y); acc.w += bhi(u1.y);
  }
  *(float4*)&sh[g][lane * 4] = acc;
  __syncthreads();
  if (t < 128) {
    float total = 0.f;
#pragma unroll
    for (int gg = 0; gg < 8; ++gg) total += sh[gg][t];
    float v = fmaxf(dinv[i] * total + bias[t], 0.f);
    float w = __shfl_xor(v, 1);
    if (!(t & 1)) outu[(long)i * 64 + (t >> 1)] = pk2(v, w);
  }
}

// ---------------- graph start offsets from sorted batch ----------------
__global__ void k_starts(const int* __restrict__ batch, int N, int* __restrict__ start) {
  int i = blockIdx.x * blockDim.x + threadIdx.x;
  int stride = gridDim.x * blockDim.x;
  for (; i < N; i += stride) {
    int g = batch[i];
    if (i == 0) {
      start[g] = 0;
    } else if (batch[i - 1] != g) {
      start[g] = i;
    }
  }
}

__global__ void k_fix_starts(int* __restrict__ start, int G, int N) {
  if (blockIdx.x == 0 && threadIdx.x == 0) {
    start[G] = N;
    for (int g = G - 1; g >= 0; --g)
      if (start[g] < 0) start[g] = start[g + 1];
  }
}

// ---------------- parallel mean-pool (batch sorted, h bf16 [N][64]) -------------
// 64 rows per block: 4 row-groups x 64 lanes (1 u32 = 2 channels per lane).
// Per-thread running sum, atomic flush at graph boundaries.
__global__ __launch_bounds__(256) void k_pool2(const unsigned* __restrict__ hu,
                                               const int* __restrict__ batch,
                                               float* __restrict__ psum, int N) {
  int t = threadIdx.x;
  int rg = t >> 6;        // row group 0..3
  int lane = t & 63;      // u32 index in row
  long base = (long)blockIdx.x * 64;
  float a0 = 0.f, a1 = 0.f;
  int cur = -1;
#pragma unroll
  for (int j = 0; j < 16; ++j) {
    long r = base + j * 4 + rg;
    if (r >= N) break;
    int g = batch[r];
    if (g != cur) {
      if (cur >= 0) {
        atomicAdd(&psum[cur * HID + lane * 2], a0);
        atomicAdd(&psum[cur * HID + lane * 2 + 1], a1);
        a0 = 0.f; a1 = 0.f;
      }
      cur = g;
    }
    unsigned u = hu[r * 64 + lane];
    a0 += blo(u); a1 += bhi(u);
  }
  if (cur >= 0) {
    atomicAdd(&psum[cur * HID + lane * 2], a0);
    atomicAdd(&psum[cur * HID + lane * 2 + 1], a1);
  }
}

// ---------------- MLP head ----------------
__global__ __launch_bounds__(128) void k_head(const float* __restrict__ psum,
                                              const int* __restrict__ gstart,
                                              const float* __restrict__ fc1w,
                                              const float* __restrict__ fc1b,
                                              const float* __restrict__ fc2w,
                                              const float* __restrict__ fc2b,
                                              float* __restrict__ out, int G) {
  __shared__ float pooled[HID];
  __shared__ float z1[HID];
  int g = blockIdx.x;
  int c = threadIdx.x;
  float cn = fmaxf((float)(gstart[g + 1] - gstart[g]), 1.f);
  pooled[c] = psum[g * HID + c] / cn;
  __syncthreads();
  float a = fc1b[c];
#pragma unroll 8
  for (int k = 0; k < HID; ++k) a += pooled[k] * fc1w[k * HID + c];
  z1[c] = fmaxf(a, 0.f);
  __syncthreads();
  if (c < 16) {
    float o = fc2b[c];
#pragma unroll 8
    for (int k = 0; k < HID; ++k) o += z1[k] * fc2w[k * 16 + c];
    out[g * 16 + c] = o;
  }
}

extern "C" void kernel_launch(void* const* d_in, const int* in_sizes, int n_in,
                              void* d_out, int out_size, void* d_ws, size_t ws_size,
                              hipStream_t stream) {
  const float* x     = (const float*)d_in[0];
  const int*   ei    = (const int*)d_in[1];
  const int*   batch = (const int*)d_in[2];
  const float* w1    = (const float*)d_in[3];
  const float* b1    = (const float*)d_in[4];
  const float* w2    = (const float*)d_in[5];
  const float* b2    = (const float*)d_in[6];
  const float* w3    = (const float*)d_in[7];
  const float* b3    = (const float*)d_in[8];
  const float* fc1w  = (const float*)d_in[9];
  const float* fc1b  = (const float*)d_in[10];
  const float* fc2w  = (const float*)d_in[11];
  const float* fc2b  = (const float*)d_in[12];
  float* out = (float*)d_out;

  const int IN = in_sizes[3] / HID;   // 260
  const int N  = in_sizes[0] / IN;    // 100000
  const int E  = in_sizes[1] / 2;     // 3200000
  const int G  = out_size / 16;       // 64

  const int* srcp = ei;
  const int* dstp = ei + E;

  // ---- workspace carve ----
  char* wsp = (char*)d_ws;
  auto alloc = [&](size_t bytes) {
    char* p = wsp;
    wsp += (bytes + 255) & ~(size_t)255;
    return p;
  };
  int*   deg      = (int*)alloc((size_t)N * 4);
  int*   rowstart = (int*)alloc((size_t)N * 4);
  int*   bsum     = (int*)alloc(1024 * 4);
  int*   boff     = (int*)alloc(1024 * 4);
  int*   bhist    = (int*)alloc(NB * 4);
  int*   bstart   = (int*)alloc((NB + 1) * 4);
  int*   gcur     = (int*)alloc(NB * 4);
  int*   gstart   = (int*)alloc((size_t)(G + 1) * 4);
  float* dinv     = (float*)alloc((size_t)N * 4);
  float* psum     = (float*)alloc((size_t)G * HID * 4);
  unsigned* Wt1   = (unsigned*)alloc(128 * 144 * 4);
  unsigned* Wt2   = (unsigned*)alloc(128 * 64 * 4);
  unsigned* Wt3   = (unsigned*)alloc(128 * 64 * 4);
  int*   csr      = (int*)alloc((size_t)E * 4);
  unsigned* bufA  = (unsigned*)alloc((size_t)N * 64 * 4);  // bf16 [N][128] packed
  unsigned* bufB  = (unsigned*)alloc((size_t)N * 64 * 4);  // bf16 [N][128] packed
  // binned edge array (E x 8B = 25.6MB) aliases bufA; consumed before first GEMM.
  unsigned long long* binned = (unsigned long long*)bufA;

  // ---- init ----
  k_fill32<<<4, 256, 0, stream>>>((int*)psum, G * HID, 0);
  k_fill32<<<1, 128, 0, stream>>>(gstart, G + 1, -1);
  k_fill32<<<1, 256, 0, stream>>>(bhist, NB, 0);

  // ---- weight prep (transpose + bf16) ----
  k_prep_w<<<72, 256, 0, stream>>>(w1, Wt1, IN, 144);
  k_prep_w<<<32, 256, 0, stream>>>(w2, Wt2, HID, 64);
  k_prep_w<<<32, 256, 0, stream>>>(w3, Wt3, HID, 64);

  // ---- binned CSR build ----
  k_hist<<<512, 256, 0, stream>>>(dstp, E, N, bhist);
  k_bscan<<<1, 1, 0, stream>>>(bhist, bstart, gcur, E);
  k_scatter<<<512, 256, 0, stream>>>(srcp, dstp, E, N, binned, gcur);
  k_bdeg<<<NB, 256, 0, stream>>>(binned, bstart, N, deg);
  k_dinv<<<(N + 255) / 256, 256, 0, stream>>>(deg, dinv, N);

  int nb = (N + SCAN_CHUNK - 1) / SCAN_CHUNK;
  k_scan_block_sums<<<nb, 256, 0, stream>>>(deg, N, bsum);
  k_scan_offsets<<<1, 1, 0, stream>>>(bsum, nb, boff);
  k_scan_write<<<nb, 256, 0, stream>>>(deg, N, boff, rowstart);
  k_place<<<NB, 256, 0, stream>>>(binned, bstart, rowstart, N, csr);

  // ---- graph boundaries ----
  k_starts<<<256, 256, 0, stream>>>(batch, N, gstart);
  k_fix_starts<<<1, 1, 0, stream>>>(gstart, G, N);

  // ---- 3 GCN layers: MFMA GEMM (epilogue scales by dinv, packs bf16) + agg ----
  int gblocks = (N + 127) / 128;
  k_gemm1_mf<<<gblocks, 256, 0, stream>>>(x, Wt1, dinv, bufA, N, IN);
  k_agg<<<N, 256, 0, stream>>>((const uint2*)bufA, dinv, rowstart, deg, csr, b1, bufB, N);

  k_gemm_mf<<<gblocks, 256, 0, stream>>>(bufB, Wt2, dinv, bufA, N);
  k_agg<<<N, 256, 0, stream>>>((const uint2*)bufA, dinv, rowstart, deg, csr, b2, bufB, N);

  k_gemm_mf<<<gblocks, 256, 0, stream>>>(bufB, Wt3, dinv, bufA, N);
  k_agg<<<N, 256, 0, stream>>>((const uint2*)bufA, dinv, rowstart, deg, csr, b3, bufB, N);

  // ---- pool + head ----
  int pblocks = (N + 63) / 64;
  k_pool2<<<pblocks, 256, 0, stream>>>(bufB, batch, psum, N);
  k_head<<<G, 128, 0, stream>>>(psum, gstart, fc1w, fc1b, fc2w, fc2b, out, G);
}

// Round 9
// 627.848 us; speedup vs baseline: 1.8495x; 1.2139x over previous
//
#include <hip/hip_runtime.h>

#define HID 128
#define SCAN_CHUNK 1024

// binned CSR build params
#define NB 256
#define BW 400
#define DEPTH 24
#define CH 2048

typedef __attribute__((ext_vector_type(8))) short bf16x8;
typedef __attribute__((ext_vector_type(4))) float f32x4;

// ---------------- bf16 helpers (RNE pack, shift unpack) ----------------
__device__ inline float blo(unsigned u) { return __uint_as_float(u << 16); }
__device__ inline float bhi(unsigned u) { return __uint_as_float(u & 0xffff0000u); }
__device__ inline unsigned rne16(float x) {
  unsigned u = __float_as_uint(x);
  return (u + 0x7fffu + ((u >> 16) & 1u)) >> 16;
}
__device__ inline unsigned pk2(float a, float b) { return (rne16(b) << 16) | rne16(a); }

// ---------------- utility: fill int buffers ----------------
__global__ void k_fill32(int* __restrict__ p, int n, int val) {
  int i = blockIdx.x * blockDim.x + threadIdx.x;
  int stride = gridDim.x * blockDim.x;
  for (; i < n; i += stride) p[i] = val;
}

// ---------------- weight transpose + bf16 pack: Wt[c][k] from W[k][c] ----------
__global__ void k_prep_w(const float* __restrict__ W, unsigned* __restrict__ Wt,
                         int K, int KP2) {
  int idx = blockIdx.x * 256 + threadIdx.x;
  int total = 128 * KP2;
  if (idx >= total) return;
  int c = idx / KP2, kk = idx - c * KP2;
  int k0 = kk * 2, k1 = k0 + 1;
  float v0 = (k0 < K) ? W[(long)k0 * 128 + c] : 0.f;
  float v1 = (k1 < K) ? W[(long)k1 * 128 + c] : 0.f;
  Wt[idx] = pk2(v0, v1);
}

// ---------------- bucket histogram (LDS-staged) ----------------
__global__ __launch_bounds__(256) void k_hist(const int* __restrict__ dst, int E, int N,
                                              int* __restrict__ bhist) {
  __shared__ int h[NB];
  int t = threadIdx.x;
  h[t] = 0;
  __syncthreads();
  int i = blockIdx.x * blockDim.x + t;
  int stride = gridDim.x * blockDim.x;
  for (; i < E; i += stride) {
    int b = (int)(((long long)dst[i] * NB) / N);
    atomicAdd(&h[b], 1);
  }
  __syncthreads();
  if (h[t]) atomicAdd(&bhist[t], h[t]);
}

__global__ void k_bscan(const int* __restrict__ bhist, int* __restrict__ bstart,
                        int* __restrict__ gcur, int E) {
  if (blockIdx.x == 0 && threadIdx.x == 0) {
    int run = 0;
    for (int b = 0; b < NB; ++b) { bstart[b] = run; gcur[b] = run; run += bhist[b]; }
    bstart[NB] = run; // == E
  }
}

// ---------------- LDS-staged scatter into bucket-major order ----------------
__global__ __launch_bounds__(256) void k_scatter(const int* __restrict__ src,
                                                 const int* __restrict__ dst,
                                                 int E, int N,
                                                 unsigned long long* __restrict__ binned,
                                                 int* __restrict__ gcur) {
  __shared__ unsigned long long buf[NB][DEPTH]; // 48 KB
  __shared__ int cnt[NB];
  int t = threadIdx.x;
  long cover = (long)gridDim.x * CH;
  int nround = (int)((E + cover - 1) / cover);
  for (int r = 0; r < nround; ++r) {
    cnt[t] = 0;
    __syncthreads();
    long base = (long)r * cover + (long)blockIdx.x * CH;
#pragma unroll
    for (int k = 0; k < CH / 256; ++k) {
      long i = base + k * 256 + t;
      if (i < E) {
        int s = src[i], d = dst[i];
        int b = (int)(((long long)d * NB) / N);
        unsigned long long pack =
            ((unsigned long long)(unsigned)d << 32) | (unsigned)s;
        int slot = atomicAdd(&cnt[b], 1);
        if (slot < DEPTH) buf[b][slot] = pack;
        else { int g = atomicAdd(&gcur[b], 1); binned[g] = pack; } // rare spill
      }
    }
    __syncthreads();
    {
      int c = cnt[t];
      if (c > DEPTH) c = DEPTH;
      if (c > 0) {
        int g = atomicAdd(&gcur[t], c);
        for (int k = 0; k < c; ++k) binned[g + k] = buf[t][k];
      }
    }
    __syncthreads();
  }
}

// ---------------- per-bucket degree histogram ----------------
__global__ __launch_bounds__(256) void k_bdeg(const unsigned long long* __restrict__ binned,
                                              const int* __restrict__ bstart, int N,
                                              int* __restrict__ deg) {
  __shared__ int hist[BW];
  int b = blockIdx.x;
  int t = threadIdx.x;
  int d0 = (int)(((long long)b * N + NB - 1) / NB);
  int d1 = (int)(((long long)(b + 1) * N + NB - 1) / NB);
  if (d1 > N) d1 = N;
  int W = d1 - d0;
  for (int w = t; w < W; w += 256) hist[w] = 0;
  __syncthreads();
  int s = bstart[b], e = bstart[b + 1];
  for (int i = s + t; i < e; i += 256) {
    int d = (int)(binned[i] >> 32);
    atomicAdd(&hist[d - d0], 1);
  }
  __syncthreads();
  for (int w = t; w < W; w += 256) deg[d0 + w] = hist[w];
}

__global__ void k_dinv(const int* __restrict__ deg, float* __restrict__ dinv, int N) {
  int i = blockIdx.x * blockDim.x + threadIdx.x;
  int stride = gridDim.x * blockDim.x;
  for (; i < N; i += stride) dinv[i] = rsqrtf((float)(deg[i] + 1)); // +1 = self loop
}

// ---------------- exclusive scan of deg -> rowstart ----------------
__global__ void k_scan_block_sums(const int* __restrict__ deg, int N, int* __restrict__ bsum) {
  __shared__ int sh[256];
  int base = blockIdx.x * SCAN_CHUNK;
  int t = threadIdx.x;
  int s = 0;
#pragma unroll
  for (int j = 0; j < 4; ++j) {
    int idx = base + t * 4 + j;
    if (idx < N) s += deg[idx];
  }
  sh[t] = s;
  __syncthreads();
  for (int off = 128; off > 0; off >>= 1) {
    if (t < off) sh[t] += sh[t + off];
    __syncthreads();
  }
  if (t == 0) bsum[blockIdx.x] = sh[0];
}

__global__ void k_scan_offsets(const int* __restrict__ bsum, int nb, int* __restrict__ boff) {
  if (blockIdx.x == 0 && threadIdx.x == 0) {
    int run = 0;
    for (int i = 0; i < nb; ++i) { boff[i] = run; run += bsum[i]; }
  }
}

__global__ void k_scan_write(const int* __restrict__ deg, int N,
                             const int* __restrict__ boff, int* __restrict__ rowstart) {
  __shared__ int sh[256];
  int base = blockIdx.x * SCAN_CHUNK;
  int t = threadIdx.x;
  int v[4];
  int s = 0;
#pragma unroll
  for (int j = 0; j < 4; ++j) {
    int idx = base + t * 4 + j;
    v[j] = (idx < N) ? deg[idx] : 0;
    s += v[j];
  }
  sh[t] = s;
  __syncthreads();
  for (int off = 1; off < 256; off <<= 1) {
    int x = 0;
    if (t >= off) x = sh[t - off];
    __syncthreads();
    sh[t] += x;
    __syncthreads();
  }
  int excl = sh[t] - s;
  int run = boff[blockIdx.x] + excl;
#pragma unroll
  for (int j = 0; j < 4; ++j) {
    int idx = base + t * 4 + j;
    if (idx < N) rowstart[idx] = run;
    run += v[j];
  }
}

// ---------------- per-bucket CSR placement with LDS cursors ----------------
__global__ __launch_bounds__(256) void k_place(const unsigned long long* __restrict__ binned,
                                               const int* __restrict__ bstart,
                                               const int* __restrict__ rowstart, int N,
                                               int* __restrict__ csr) {
  __shared__ int cur[BW];
  int b = blockIdx.x;
  int t = threadIdx.x;
  int d0 = (int)(((long long)b * N + NB - 1) / NB);
  int d1 = (int)(((long long)(b + 1) * N + NB - 1) / NB);
  if (d1 > N) d1 = N;
  int W = d1 - d0;
  for (int w = t; w < W; w += 256) cur[w] = 0;
  __syncthreads();
  int s = bstart[b], e = bstart[b + 1];
  for (int i = s + t; i < e; i += 256) {
    unsigned long long p = binned[i];
    int d = (int)(p >> 32);
    int sn = (int)(p & 0xffffffffu);
    int pos = rowstart[d] + atomicAdd(&cur[d - d0], 1);
    csr[pos] = sn;
  }
}

// ============ MFMA GEMM, layers 2/3: Cbf16 = dinv(row)*(Abf16[N][128] @ W[128][128]) ==
__global__ __launch_bounds__(256) void k_gemm_mf(const unsigned* __restrict__ A,
                                                 const unsigned* __restrict__ Wt,
                                                 const float* __restrict__ dscale,
                                                 unsigned* __restrict__ Cu, int N) {
  int t = threadIdx.x;
  int w = t >> 6;
  int l = t & 63;
  int lr = l & 15;
  int kg = l >> 4;
  int wr0 = blockIdx.x * 128 + w * 32;

  f32x4 acc[2][8];
#pragma unroll
  for (int rt = 0; rt < 2; ++rt)
#pragma unroll
    for (int f = 0; f < 8; ++f) acc[rt][f] = (f32x4){0.f, 0.f, 0.f, 0.f};

  int r0 = wr0 + lr, r1 = wr0 + 16 + lr;
#pragma unroll
  for (int kt = 0; kt < 4; ++kt) {
    int ko = kt * 16 + kg * 4;
    bf16x8 a0 = {}, a1 = {};
    if (r0 < N) a0 = *(const bf16x8*)&A[(long)r0 * 64 + ko];
    if (r1 < N) a1 = *(const bf16x8*)&A[(long)r1 * 64 + ko];
#pragma unroll
    for (int f = 0; f < 8; ++f) {
      bf16x8 b = *(const bf16x8*)&Wt[(f * 16 + lr) * 64 + ko];
      acc[0][f] = __builtin_amdgcn_mfma_f32_16x16x32_bf16(a0, b, acc[0][f], 0, 0, 0);
      acc[1][f] = __builtin_amdgcn_mfma_f32_16x16x32_bf16(a1, b, acc[1][f], 0, 0, 0);
    }
  }
#pragma unroll
  for (int rt = 0; rt < 2; ++rt) {
#pragma unroll
    for (int reg = 0; reg < 4; ++reg) {
      int row = wr0 + rt * 16 + kg * 4 + reg;
      float ds = (row < N) ? dscale[row] : 0.f;
#pragma unroll
      for (int f = 0; f < 8; ++f) {
        float v = acc[rt][f][reg] * ds;
        float pv = __shfl_xor(v, 1);
        if (!(l & 1) && row < N)
          Cu[(long)row * 64 + ((f * 16 + lr) >> 1)] = pk2(v, pv);
      }
    }
  }
}

// ============ MFMA GEMM, layer 1: x f32 -> bf16 in-flight ============
__global__ __launch_bounds__(256) void k_gemm1_mf(const float* __restrict__ X,
                                                  const unsigned* __restrict__ Wt,
                                                  const float* __restrict__ dscale,
                                                  unsigned* __restrict__ Cu, int N, int K) {
  int t = threadIdx.x;
  int w = t >> 6;
  int l = t & 63;
  int lr = l & 15;
  int kg = l >> 4;
  int wr0 = blockIdx.x * 128 + w * 32;

  f32x4 acc[2][8];
#pragma unroll
  for (int rt = 0; rt < 2; ++rt)
#pragma unroll
    for (int f = 0; f < 8; ++f) acc[rt][f] = (f32x4){0.f, 0.f, 0.f, 0.f};

  int r0 = wr0 + lr, r1 = wr0 + 16 + lr;
  int nkt = (K + 31) / 32;  // 9 for K=260
  for (int kt = 0; kt < nkt; ++kt) {
    int kb = kt * 32 + kg * 8;
    bf16x8 a0 = {}, a1 = {};
    if (kb + 7 < K) {
      if (r0 < N) {
        const float* p = &X[(long)r0 * K + kb];
        float4 u = *(const float4*)p, v = *(const float4*)(p + 4);
        union { uint4 q; bf16x8 b; } cv;
        cv.q.x = pk2(u.x, u.y); cv.q.y = pk2(u.z, u.w);
        cv.q.z = pk2(v.x, v.y); cv.q.w = pk2(v.z, v.w);
        a0 = cv.b;
      }
      if (r1 < N) {
        const float* p = &X[(long)r1 * K + kb];
        float4 u = *(const float4*)p, v = *(const float4*)(p + 4);
        union { uint4 q; bf16x8 b; } cv;
        cv.q.x = pk2(u.x, u.y); cv.q.y = pk2(u.z, u.w);
        cv.q.z = pk2(v.x, v.y); cv.q.w = pk2(v.z, v.w);
        a1 = cv.b;
      }
    } else if (kb < K) {  // partial tail (k=256..259)
      float t0[8], t1[8];
#pragma unroll
      for (int j = 0; j < 8; ++j) {
        int k = kb + j;
        t0[j] = (r0 < N && k < K) ? X[(long)r0 * K + k] : 0.f;
        t1[j] = (r1 < N && k < K) ? X[(long)r1 * K + k] : 0.f;
      }
      union { uint4 q; bf16x8 b; } c0, c1;
      c0.q.x = pk2(t0[0], t0[1]); c0.q.y = pk2(t0[2], t0[3]);
      c0.q.z = pk2(t0[4], t0[5]); c0.q.w = pk2(t0[6], t0[7]);
      c1.q.x = pk2(t1[0], t1[1]); c1.q.y = pk2(t1[2], t1[3]);
      c1.q.z = pk2(t1[4], t1[5]); c1.q.w = pk2(t1[6], t1[7]);
      a0 = c0.b; a1 = c1.b;
    }
    int ko = kt * 16 + kg * 4;
#pragma unroll
    for (int f = 0; f < 8; ++f) {
      bf16x8 b = *(const bf16x8*)&Wt[(f * 16 + lr) * 144 + ko];
      acc[0][f] = __builtin_amdgcn_mfma_f32_16x16x32_bf16(a0, b, acc[0][f], 0, 0, 0);
      acc[1][f] = __builtin_amdgcn_mfma_f32_16x16x32_bf16(a1, b, acc[1][f], 0, 0, 0);
    }
  }
#pragma unroll
  for (int rt = 0; rt < 2; ++rt) {
#pragma unroll
    for (int reg = 0; reg < 4; ++reg) {
      int row = wr0 + rt * 16 + kg * 4 + reg;
      float ds = (row < N) ? dscale[row] : 0.f;
#pragma unroll
      for (int f = 0; f < 8; ++f) {
        float v = acc[rt][f][reg] * ds;
        float pv = __shfl_xor(v, 1);
        if (!(l & 1) && row < N)
          Cu[(long)row * 64 + ((f * 16 + lr) >> 1)] = pk2(v, pv);
      }
    }
  }
}

// ---------------- pull aggregation v3: 32-lane group per node, no LDS ----------
// 8 nodes per 256-block. 4-deep unrolled gather for MLP.
// out[i][c] = relu( dinv[i]*(T[i][c] + sum_nbr T[s][c]) + b[c] ), bf16-packed.
__global__ __launch_bounds__(256) void k_agg(const uint2* __restrict__ T,   // [N][32]
                                             const float* __restrict__ dinv,
                                             const int* __restrict__ rowstart,
                                             const int* __restrict__ deg,
                                             const int* __restrict__ csr,
                                             const float* __restrict__ bias,
                                             unsigned* __restrict__ outu,   // [N][64]
                                             int N) {
  int t = threadIdx.x;
  int grp = t >> 5;        // node slot 0..7
  int lane = t & 31;       // uint2 slot in row (4 channels)
  int i = blockIdx.x * 8 + grp;
  if (i >= N) return;

  uint2 su = T[(long)i * 32 + lane];  // self-loop (pre-scaled)
  float ax = blo(su.x), ay = bhi(su.x), az = blo(su.y), aw = bhi(su.y);

  int s0 = rowstart[i];
  int d = deg[i];
  int j = 0;
  for (; j + 3 < d; j += 4) {
    int s1 = csr[s0 + j];
    int s2 = csr[s0 + j + 1];
    int s3 = csr[s0 + j + 2];
    int s4 = csr[s0 + j + 3];
    uint2 u1 = T[(long)s1 * 32 + lane];
    uint2 u2 = T[(long)s2 * 32 + lane];
    uint2 u3 = T[(long)s3 * 32 + lane];
    uint2 u4 = T[(long)s4 * 32 + lane];
    ax += (blo(u1.x) + blo(u2.x)) + (blo(u3.x) + blo(u4.x));
    ay += (bhi(u1.x) + bhi(u2.x)) + (bhi(u3.x) + bhi(u4.x));
    az += (blo(u1.y) + blo(u2.y)) + (blo(u3.y) + blo(u4.y));
    aw += (bhi(u1.y) + bhi(u2.y)) + (bhi(u3.y) + bhi(u4.y));
  }
  for (; j < d; ++j) {
    int s1 = csr[s0 + j];
    uint2 u1 = T[(long)s1 * 32 + lane];
    ax += blo(u1.x); ay += bhi(u1.x); az += blo(u1.y); aw += bhi(u1.y);
  }
  float di = dinv[i];
  int c0 = lane * 4;
  float v0 = fmaxf(di * ax + bias[c0 + 0], 0.f);
  float v1 = fmaxf(di * ay + bias[c0 + 1], 0.f);
  float v2 = fmaxf(di * az + bias[c0 + 2], 0.f);
  float v3 = fmaxf(di * aw + bias[c0 + 3], 0.f);
  *(uint2*)&outu[(long)i * 64 + lane * 2] = make_uint2(pk2(v0, v1), pk2(v2, v3));
}

// ---------------- graph start offsets from sorted batch ----------------
__global__ void k_starts(const int* __restrict__ batch, int N, int* __restrict__ start) {
  int i = blockIdx.x * blockDim.x + threadIdx.x;
  int stride = gridDim.x * blockDim.x;
  for (; i < N; i += stride) {
    int g = batch[i];
    if (i == 0) {
      start[g] = 0;
    } else if (batch[i - 1] != g) {
      start[g] = i;
    }
  }
}

__global__ void k_fix_starts(int* __restrict__ start, int G, int N) {
  if (blockIdx.x == 0 && threadIdx.x == 0) {
    start[G] = N;
    for (int g = G - 1; g >= 0; --g)
      if (start[g] < 0) start[g] = start[g + 1];
  }
}

// ---------------- parallel mean-pool (batch sorted, h bf16 [N][64]) -------------
__global__ __launch_bounds__(256) void k_pool2(const unsigned* __restrict__ hu,
                                               const int* __restrict__ batch,
                                               float* __restrict__ psum, int N) {
  int t = threadIdx.x;
  int rg = t >> 6;        // row group 0..3
  int lane = t & 63;      // u32 index in row
  long base = (long)blockIdx.x * 64;
  float a0 = 0.f, a1 = 0.f;
  int cur = -1;
#pragma unroll
  for (int j = 0; j < 16; ++j) {
    long r = base + j * 4 + rg;
    if (r >= N) break;
    int g = batch[r];
    if (g != cur) {
      if (cur >= 0) {
        atomicAdd(&psum[cur * HID + lane * 2], a0);
        atomicAdd(&psum[cur * HID + lane * 2 + 1], a1);
        a0 = 0.f; a1 = 0.f;
      }
      cur = g;
    }
    unsigned u = hu[r * 64 + lane];
    a0 += blo(u); a1 += bhi(u);
  }
  if (cur >= 0) {
    atomicAdd(&psum[cur * HID + lane * 2], a0);
    atomicAdd(&psum[cur * HID + lane * 2 + 1], a1);
  }
}

// ---------------- MLP head ----------------
__global__ __launch_bounds__(128) void k_head(const float* __restrict__ psum,
                                              const int* __restrict__ gstart,
                                              const float* __restrict__ fc1w,
                                              const float* __restrict__ fc1b,
                                              const float* __restrict__ fc2w,
                                              const float* __restrict__ fc2b,
                                              float* __restrict__ out, int G) {
  __shared__ float pooled[HID];
  __shared__ float z1[HID];
  int g = blockIdx.x;
  int c = threadIdx.x;
  float cn = fmaxf((float)(gstart[g + 1] - gstart[g]), 1.f);
  pooled[c] = psum[g * HID + c] / cn;
  __syncthreads();
  float a = fc1b[c];
#pragma unroll 8
  for (int k = 0; k < HID; ++k) a += pooled[k] * fc1w[k * HID + c];
  z1[c] = fmaxf(a, 0.f);
  __syncthreads();
  if (c < 16) {
    float o = fc2b[c];
#pragma unroll 8
    for (int k = 0; k < HID; ++k) o += z1[k] * fc2w[k * 16 + c];
    out[g * 16 + c] = o;
  }
}

extern "C" void kernel_launch(void* const* d_in, const int* in_sizes, int n_in,
                              void* d_out, int out_size, void* d_ws, size_t ws_size,
                              hipStream_t stream) {
  const float* x     = (const float*)d_in[0];
  const int*   ei    = (const int*)d_in[1];
  const int*   batch = (const int*)d_in[2];
  const float* w1    = (const float*)d_in[3];
  const float* b1    = (const float*)d_in[4];
  const float* w2    = (const float*)d_in[5];
  const float* b2    = (const float*)d_in[6];
  const float* w3    = (const float*)d_in[7];
  const float* b3    = (const float*)d_in[8];
  const float* fc1w  = (const float*)d_in[9];
  const float* fc1b  = (const float*)d_in[10];
  const float* fc2w  = (const float*)d_in[11];
  const float* fc2b  = (const float*)d_in[12];
  float* out = (float*)d_out;

  const int IN = in_sizes[3] / HID;   // 260
  const int N  = in_sizes[0] / IN;    // 100000
  const int E  = in_sizes[1] / 2;     // 3200000
  const int G  = out_size / 16;       // 64

  const int* srcp = ei;
  const int* dstp = ei + E;

  // ---- workspace carve ----
  char* wsp = (char*)d_ws;
  auto alloc = [&](size_t bytes) {
    char* p = wsp;
    wsp += (bytes + 255) & ~(size_t)255;
    return p;
  };
  int*   deg      = (int*)alloc((size_t)N * 4);
  int*   rowstart = (int*)alloc((size_t)N * 4);
  int*   bsum     = (int*)alloc(1024 * 4);
  int*   boff     = (int*)alloc(1024 * 4);
  int*   bhist    = (int*)alloc(NB * 4);
  int*   bstart   = (int*)alloc((NB + 1) * 4);
  int*   gcur     = (int*)alloc(NB * 4);
  int*   gstart   = (int*)alloc((size_t)(G + 1) * 4);
  float* dinv     = (float*)alloc((size_t)N * 4);
  float* psum     = (float*)alloc((size_t)G * HID * 4);
  unsigned* Wt1   = (unsigned*)alloc(128 * 144 * 4);
  unsigned* Wt2   = (unsigned*)alloc(128 * 64 * 4);
  unsigned* Wt3   = (unsigned*)alloc(128 * 64 * 4);
  int*   csr      = (int*)alloc((size_t)E * 4);
  unsigned* bufA  = (unsigned*)alloc((size_t)N * 64 * 4);  // bf16 [N][128] packed
  unsigned* bufB  = (unsigned*)alloc((size_t)N * 64 * 4);  // bf16 [N][128] packed
  // binned edge array (E x 8B = 25.6MB) aliases bufA; consumed before first GEMM.
  unsigned long long* binned = (unsigned long long*)bufA;

  // ---- init ----
  k_fill32<<<4, 256, 0, stream>>>((int*)psum, G * HID, 0);
  k_fill32<<<1, 128, 0, stream>>>(gstart, G + 1, -1);
  k_fill32<<<1, 256, 0, stream>>>(bhist, NB, 0);

  // ---- weight prep (transpose + bf16) ----
  k_prep_w<<<72, 256, 0, stream>>>(w1, Wt1, IN, 144);
  k_prep_w<<<32, 256, 0, stream>>>(w2, Wt2, HID, 64);
  k_prep_w<<<32, 256, 0, stream>>>(w3, Wt3, HID, 64);

  // ---- binned CSR build ----
  k_hist<<<512, 256, 0, stream>>>(dstp, E, N, bhist);
  k_bscan<<<1, 1, 0, stream>>>(bhist, bstart, gcur, E);
  k_scatter<<<1024, 256, 0, stream>>>(srcp, dstp, E, N, binned, gcur);
  k_bdeg<<<NB, 256, 0, stream>>>(binned, bstart, N, deg);
  k_dinv<<<(N + 255) / 256, 256, 0, stream>>>(deg, dinv, N);

  int nb = (N + SCAN_CHUNK - 1) / SCAN_CHUNK;
  k_scan_block_sums<<<nb, 256, 0, stream>>>(deg, N, bsum);
  k_scan_offsets<<<1, 1, 0, stream>>>(bsum, nb, boff);
  k_scan_write<<<nb, 256, 0, stream>>>(deg, N, boff, rowstart);
  k_place<<<NB, 256, 0, stream>>>(binned, bstart, rowstart, N, csr);

  // ---- graph boundaries ----
  k_starts<<<256, 256, 0, stream>>>(batch, N, gstart);
  k_fix_starts<<<1, 1, 0, stream>>>(gstart, G, N);

  // ---- 3 GCN layers: MFMA GEMM (epilogue scales by dinv, packs bf16) + agg ----
  int gblocks = (N + 127) / 128;
  int ablocks = (N + 7) / 8;
  k_gemm1_mf<<<gblocks, 256, 0, stream>>>(x, Wt1, dinv, bufA, N, IN);
  k_agg<<<ablocks, 256, 0, stream>>>((const uint2*)bufA, dinv, rowstart, deg, csr, b1, bufB, N);

  k_gemm_mf<<<gblocks, 256, 0, stream>>>(bufB, Wt2, dinv, bufA, N);
  k_agg<<<ablocks, 256, 0, stream>>>((const uint2*)bufA, dinv, rowstart, deg, csr, b2, bufB, N);

  k_gemm_mf<<<gblocks, 256, 0, stream>>>(bufB, Wt3, dinv, bufA, N);
  k_agg<<<ablocks, 256, 0, stream>>>((const uint2*)bufA, dinv, rowstart, deg, csr, b3, bufB, N);

  // ---- pool + head ----
  int pblocks = (N + 63) / 64;
  k_pool2<<<pblocks, 256, 0, stream>>>(bufB, batch, psum, N);
  k_head<<<G, 128, 0, stream>>>(psum, gstart, fc1w, fc1b, fc2w, fc2b, out, G);
}

// Round 10
// 615.314 us; speedup vs baseline: 1.8872x; 1.0204x over previous
//
#include <hip/hip_runtime.h>

#define HID 128
#define SCAN_CHUNK 1024

// binned CSR build params
#define NB 256
#define BW 400
#define DEPTH 24
#define CH 2048

typedef __attribute__((ext_vector_type(8))) short bf16x8;
typedef __attribute__((ext_vector_type(4))) float f32x4;

// ---------------- bf16 helpers (RNE pack, shift unpack) ----------------
__device__ inline float blo(unsigned u) { return __uint_as_float(u << 16); }
__device__ inline float bhi(unsigned u) { return __uint_as_float(u & 0xffff0000u); }
__device__ inline unsigned rne16(float x) {
  unsigned u = __float_as_uint(x);
  return (u + 0x7fffu + ((u >> 16) & 1u)) >> 16;
}
__device__ inline unsigned pk2(float a, float b) { return (rne16(b) << 16) | rne16(a); }

// ---------------- fused init: psum=0, gstart=-1, bhist=0 ----------------
__global__ void k_init(float* __restrict__ psum, int* __restrict__ gstart,
                       int* __restrict__ bhist, int G) {
  int i = blockIdx.x * 256 + threadIdx.x;
  if (i < G * HID) psum[i] = 0.f;
  if (i <= G) gstart[i] = -1;
  if (i < NB) bhist[i] = 0;
}

// ---------------- fused weight transpose + bf16 pack (all 3 layers) -------------
__device__ inline void prep_one(const float* __restrict__ W, unsigned* __restrict__ Wt,
                                int K, int KP2, int b) {
  int idx = b * 256 + threadIdx.x;
  if (idx >= 128 * KP2) return;
  int c = idx / KP2, kk = idx - c * KP2;
  int k0 = kk * 2, k1 = k0 + 1;
  float v0 = (k0 < K) ? W[(long)k0 * 128 + c] : 0.f;
  float v1 = (k1 < K) ? W[(long)k1 * 128 + c] : 0.f;
  Wt[idx] = pk2(v0, v1);
}

__global__ void k_prep_w3(const float* __restrict__ w1, const float* __restrict__ w2,
                          const float* __restrict__ w3, unsigned* __restrict__ Wt1,
                          unsigned* __restrict__ Wt2, unsigned* __restrict__ Wt3,
                          int IN) {
  int b = blockIdx.x;
  if (b < 72) prep_one(w1, Wt1, IN, 144, b);
  else if (b < 104) prep_one(w2, Wt2, 128, 64, b - 72);
  else prep_one(w3, Wt3, 128, 64, b - 104);
}

// ---------------- bucket histogram (LDS-staged) ----------------
__global__ __launch_bounds__(256) void k_hist(const int* __restrict__ dst, int E, int N,
                                              int* __restrict__ bhist) {
  __shared__ int h[NB];
  int t = threadIdx.x;
  h[t] = 0;
  __syncthreads();
  int i = blockIdx.x * blockDim.x + t;
  int stride = gridDim.x * blockDim.x;
  for (; i < E; i += stride) {
    int b = (int)(((long long)dst[i] * NB) / N);
    atomicAdd(&h[b], 1);
  }
  __syncthreads();
  if (h[t]) atomicAdd(&bhist[t], h[t]);
}

__global__ void k_bscan(const int* __restrict__ bhist, int* __restrict__ bstart,
                        int* __restrict__ gcur, int E) {
  if (blockIdx.x == 0 && threadIdx.x == 0) {
    int run = 0;
    for (int b = 0; b < NB; ++b) { bstart[b] = run; gcur[b] = run; run += bhist[b]; }
    bstart[NB] = run; // == E
  }
}

// ---------------- LDS-staged scatter into bucket-major order ----------------
__global__ __launch_bounds__(256) void k_scatter(const int* __restrict__ src,
                                                 const int* __restrict__ dst,
                                                 int E, int N,
                                                 unsigned long long* __restrict__ binned,
                                                 int* __restrict__ gcur) {
  __shared__ unsigned long long buf[NB][DEPTH]; // 48 KB
  __shared__ int cnt[NB];
  int t = threadIdx.x;
  long cover = (long)gridDim.x * CH;
  int nround = (int)((E + cover - 1) / cover);
  for (int r = 0; r < nround; ++r) {
    cnt[t] = 0;
    __syncthreads();
    long base = (long)r * cover + (long)blockIdx.x * CH;
#pragma unroll
    for (int k = 0; k < CH / 256; ++k) {
      long i = base + k * 256 + t;
      if (i < E) {
        int s = src[i], d = dst[i];
        int b = (int)(((long long)d * NB) / N);
        unsigned long long pack =
            ((unsigned long long)(unsigned)d << 32) | (unsigned)s;
        int slot = atomicAdd(&cnt[b], 1);
        if (slot < DEPTH) buf[b][slot] = pack;
        else { int g = atomicAdd(&gcur[b], 1); binned[g] = pack; } // rare spill
      }
    }
    __syncthreads();
    {
      int c = cnt[t];
      if (c > DEPTH) c = DEPTH;
      if (c > 0) {
        int g = atomicAdd(&gcur[t], c);
        for (int k = 0; k < c; ++k) binned[g + k] = buf[t][k];
      }
    }
    __syncthreads();
  }
}

// ---------------- per-bucket degree histogram + fused dinv ----------------
__global__ __launch_bounds__(256) void k_bdeg(const unsigned long long* __restrict__ binned,
                                              const int* __restrict__ bstart, int N,
                                              int* __restrict__ deg,
                                              float* __restrict__ dinv) {
  __shared__ int hist[BW];
  int b = blockIdx.x;
  int t = threadIdx.x;
  int d0 = (int)(((long long)b * N + NB - 1) / NB);
  int d1 = (int)(((long long)(b + 1) * N + NB - 1) / NB);
  if (d1 > N) d1 = N;
  int W = d1 - d0;
  for (int w = t; w < W; w += 256) hist[w] = 0;
  __syncthreads();
  int s = bstart[b], e = bstart[b + 1];
  for (int i = s + t; i < e; i += 256) {
    int d = (int)(binned[i] >> 32);
    atomicAdd(&hist[d - d0], 1);
  }
  __syncthreads();
  for (int w = t; w < W; w += 256) {
    int dv = hist[w];
    deg[d0 + w] = dv;
    dinv[d0 + w] = rsqrtf((float)(dv + 1)); // +1 = self loop
  }
}

// ---------------- exclusive scan of deg -> rowstart ----------------
__global__ void k_scan_block_sums(const int* __restrict__ deg, int N, int* __restrict__ bsum) {
  __shared__ int sh[256];
  int base = blockIdx.x * SCAN_CHUNK;
  int t = threadIdx.x;
  int s = 0;
#pragma unroll
  for (int j = 0; j < 4; ++j) {
    int idx = base + t * 4 + j;
    if (idx < N) s += deg[idx];
  }
  sh[t] = s;
  __syncthreads();
  for (int off = 128; off > 0; off >>= 1) {
    if (t < off) sh[t] += sh[t + off];
    __syncthreads();
  }
  if (t == 0) bsum[blockIdx.x] = sh[0];
}

__global__ void k_scan_offsets(const int* __restrict__ bsum, int nb, int* __restrict__ boff) {
  if (blockIdx.x == 0 && threadIdx.x == 0) {
    int run = 0;
    for (int i = 0; i < nb; ++i) { boff[i] = run; run += bsum[i]; }
  }
}

__global__ void k_scan_write(const int* __restrict__ deg, int N,
                             const int* __restrict__ boff, int* __restrict__ rowstart) {
  __shared__ int sh[256];
  int base = blockIdx.x * SCAN_CHUNK;
  int t = threadIdx.x;
  int v[4];
  int s = 0;
#pragma unroll
  for (int j = 0; j < 4; ++j) {
    int idx = base + t * 4 + j;
    v[j] = (idx < N) ? deg[idx] : 0;
    s += v[j];
  }
  sh[t] = s;
  __syncthreads();
  for (int off = 1; off < 256; off <<= 1) {
    int x = 0;
    if (t >= off) x = sh[t - off];
    __syncthreads();
    sh[t] += x;
    __syncthreads();
  }
  int excl = sh[t] - s;
  int run = boff[blockIdx.x] + excl;
#pragma unroll
  for (int j = 0; j < 4; ++j) {
    int idx = base + t * 4 + j;
    if (idx < N) rowstart[idx] = run;
    run += v[j];
  }
}

// ---------------- per-bucket CSR placement with LDS cursors ----------------
__global__ __launch_bounds__(256) void k_place(const unsigned long long* __restrict__ binned,
                                               const int* __restrict__ bstart,
                                               const int* __restrict__ rowstart, int N,
                                               int* __restrict__ csr) {
  __shared__ int cur[BW];
  int b = blockIdx.x;
  int t = threadIdx.x;
  int d0 = (int)(((long long)b * N + NB - 1) / NB);
  int d1 = (int)(((long long)(b + 1) * N + NB - 1) / NB);
  if (d1 > N) d1 = N;
  int W = d1 - d0;
  for (int w = t; w < W; w += 256) cur[w] = 0;
  __syncthreads();
  int s = bstart[b], e = bstart[b + 1];
  for (int i = s + t; i < e; i += 256) {
    unsigned long long p = binned[i];
    int d = (int)(p >> 32);
    int sn = (int)(p & 0xffffffffu);
    int pos = rowstart[d] + atomicAdd(&cur[d - d0], 1);
    csr[pos] = sn;
  }
}

// ============ MFMA GEMM, layers 2/3: Cbf16 = dinv(row)*(Abf16[N][128] @ W[128][128]) ==
__global__ __launch_bounds__(256) void k_gemm_mf(const unsigned* __restrict__ A,
                                                 const unsigned* __restrict__ Wt,
                                                 const float* __restrict__ dscale,
                                                 unsigned* __restrict__ Cu, int N) {
  int t = threadIdx.x;
  int w = t >> 6;
  int l = t & 63;
  int lr = l & 15;
  int kg = l >> 4;
  int wr0 = blockIdx.x * 128 + w * 32;

  f32x4 acc[2][8];
#pragma unroll
  for (int rt = 0; rt < 2; ++rt)
#pragma unroll
    for (int f = 0; f < 8; ++f) acc[rt][f] = (f32x4){0.f, 0.f, 0.f, 0.f};

  int r0 = wr0 + lr, r1 = wr0 + 16 + lr;
#pragma unroll
  for (int kt = 0; kt < 4; ++kt) {
    int ko = kt * 16 + kg * 4;
    bf16x8 a0 = {}, a1 = {};
    if (r0 < N) a0 = *(const bf16x8*)&A[(long)r0 * 64 + ko];
    if (r1 < N) a1 = *(const bf16x8*)&A[(long)r1 * 64 + ko];
#pragma unroll
    for (int f = 0; f < 8; ++f) {
      bf16x8 b = *(const bf16x8*)&Wt[(f * 16 + lr) * 64 + ko];
      acc[0][f] = __builtin_amdgcn_mfma_f32_16x16x32_bf16(a0, b, acc[0][f], 0, 0, 0);
      acc[1][f] = __builtin_amdgcn_mfma_f32_16x16x32_bf16(a1, b, acc[1][f], 0, 0, 0);
    }
  }
#pragma unroll
  for (int rt = 0; rt < 2; ++rt) {
#pragma unroll
    for (int reg = 0; reg < 4; ++reg) {
      int row = wr0 + rt * 16 + kg * 4 + reg;
      float ds = (row < N) ? dscale[row] : 0.f;
#pragma unroll
      for (int f = 0; f < 8; ++f) {
        float v = acc[rt][f][reg] * ds;
        float pv = __shfl_xor(v, 1);
        if (!(l & 1) && row < N)
          Cu[(long)row * 64 + ((f * 16 + lr) >> 1)] = pk2(v, pv);
      }
    }
  }
}

// ============ MFMA GEMM, layer 1: x f32 -> bf16 in-flight ============
__global__ __launch_bounds__(256) void k_gemm1_mf(const float* __restrict__ X,
                                                  const unsigned* __restrict__ Wt,
                                                  const float* __restrict__ dscale,
                                                  unsigned* __restrict__ Cu, int N, int K) {
  int t = threadIdx.x;
  int w = t >> 6;
  int l = t & 63;
  int lr = l & 15;
  int kg = l >> 4;
  int wr0 = blockIdx.x * 128 + w * 32;

  f32x4 acc[2][8];
#pragma unroll
  for (int rt = 0; rt < 2; ++rt)
#pragma unroll
    for (int f = 0; f < 8; ++f) acc[rt][f] = (f32x4){0.f, 0.f, 0.f, 0.f};

  int r0 = wr0 + lr, r1 = wr0 + 16 + lr;
  int nkt = (K + 31) / 32;  // 9 for K=260
  for (int kt = 0; kt < nkt; ++kt) {
    int kb = kt * 32 + kg * 8;
    bf16x8 a0 = {}, a1 = {};
    if (kb + 7 < K) {
      if (r0 < N) {
        const float* p = &X[(long)r0 * K + kb];
        float4 u = *(const float4*)p, v = *(const float4*)(p + 4);
        union { uint4 q; bf16x8 b; } cv;
        cv.q.x = pk2(u.x, u.y); cv.q.y = pk2(u.z, u.w);
        cv.q.z = pk2(v.x, v.y); cv.q.w = pk2(v.z, v.w);
        a0 = cv.b;
      }
      if (r1 < N) {
        const float* p = &X[(long)r1 * K + kb];
        float4 u = *(const float4*)p, v = *(const float4*)(p + 4);
        union { uint4 q; bf16x8 b; } cv;
        cv.q.x = pk2(u.x, u.y); cv.q.y = pk2(u.z, u.w);
        cv.q.z = pk2(v.x, v.y); cv.q.w = pk2(v.z, v.w);
        a1 = cv.b;
      }
    } else if (kb < K) {  // partial tail (k=256..259)
      float t0[8], t1[8];
#pragma unroll
      for (int j = 0; j < 8; ++j) {
        int k = kb + j;
        t0[j] = (r0 < N && k < K) ? X[(long)r0 * K + k] : 0.f;
        t1[j] = (r1 < N && k < K) ? X[(long)r1 * K + k] : 0.f;
      }
      union { uint4 q; bf16x8 b; } c0, c1;
      c0.q.x = pk2(t0[0], t0[1]); c0.q.y = pk2(t0[2], t0[3]);
      c0.q.z = pk2(t0[4], t0[5]); c0.q.w = pk2(t0[6], t0[7]);
      c1.q.x = pk2(t1[0], t1[1]); c1.q.y = pk2(t1[2], t1[3]);
      c1.q.z = pk2(t1[4], t1[5]); c1.q.w = pk2(t1[6], t1[7]);
      a0 = c0.b; a1 = c1.b;
    }
    int ko = kt * 16 + kg * 4;
#pragma unroll
    for (int f = 0; f < 8; ++f) {
      bf16x8 b = *(const bf16x8*)&Wt[(f * 16 + lr) * 144 + ko];
      acc[0][f] = __builtin_amdgcn_mfma_f32_16x16x32_bf16(a0, b, acc[0][f], 0, 0, 0);
      acc[1][f] = __builtin_amdgcn_mfma_f32_16x16x32_bf16(a1, b, acc[1][f], 0, 0, 0);
    }
  }
#pragma unroll
  for (int rt = 0; rt < 2; ++rt) {
#pragma unroll
    for (int reg = 0; reg < 4; ++reg) {
      int row = wr0 + rt * 16 + kg * 4 + reg;
      float ds = (row < N) ? dscale[row] : 0.f;
#pragma unroll
      for (int f = 0; f < 8; ++f) {
        float v = acc[rt][f][reg] * ds;
        float pv = __shfl_xor(v, 1);
        if (!(l & 1) && row < N)
          Cu[(long)row * 64 + ((f * 16 + lr) >> 1)] = pk2(v, pv);
      }
    }
  }
}

// ---------------- pull aggregation v4: 16 lanes x uint4 per node ----------------
// 16 nodes per 256-block; 4-deep unrolled gather (4 full rows in flight per
// 16-lane group). out[i][c] = relu(dinv[i]*(T[i][c]+sum T[s][c]) + b[c]).
__global__ __launch_bounds__(256) void k_agg(const uint4* __restrict__ T4,  // [N][16]
                                             const float* __restrict__ dinv,
                                             const int* __restrict__ rowstart,
                                             const int* __restrict__ deg,
                                             const int* __restrict__ csr,
                                             const float* __restrict__ bias,
                                             uint4* __restrict__ outu,      // [N][16]
                                             int N) {
  int t = threadIdx.x;
  int grp = t >> 4;        // node slot 0..15
  int lane = t & 15;       // uint4 slot in row (8 channels)
  int i = blockIdx.x * 16 + grp;
  if (i >= N) return;

  int c0 = lane * 8;
  float b0 = bias[c0 + 0], b1 = bias[c0 + 1], b2 = bias[c0 + 2], b3 = bias[c0 + 3];
  float b4 = bias[c0 + 4], b5 = bias[c0 + 5], b6 = bias[c0 + 6], b7 = bias[c0 + 7];

  uint4 su = T4[(long)i * 16 + lane];  // self-loop (pre-scaled)
  float a0 = blo(su.x), a1 = bhi(su.x), a2 = blo(su.y), a3 = bhi(su.y);
  float a4 = blo(su.z), a5 = bhi(su.z), a6 = blo(su.w), a7 = bhi(su.w);

  int s0 = rowstart[i];
  int d = deg[i];
  int j = 0;
  for (; j + 3 < d; j += 4) {
    int n1 = csr[s0 + j];
    int n2 = csr[s0 + j + 1];
    int n3 = csr[s0 + j + 2];
    int n4 = csr[s0 + j + 3];
    uint4 u1 = T4[(long)n1 * 16 + lane];
    uint4 u2 = T4[(long)n2 * 16 + lane];
    uint4 u3 = T4[(long)n3 * 16 + lane];
    uint4 u4 = T4[(long)n4 * 16 + lane];
    a0 += (blo(u1.x) + blo(u2.x)) + (blo(u3.x) + blo(u4.x));
    a1 += (bhi(u1.x) + bhi(u2.x)) + (bhi(u3.x) + bhi(u4.x));
    a2 += (blo(u1.y) + blo(u2.y)) + (blo(u3.y) + blo(u4.y));
    a3 += (bhi(u1.y) + bhi(u2.y)) + (bhi(u3.y) + bhi(u4.y));
    a4 += (blo(u1.z) + blo(u2.z)) + (blo(u3.z) + blo(u4.z));
    a5 += (bhi(u1.z) + bhi(u2.z)) + (bhi(u3.z) + bhi(u4.z));
    a6 += (blo(u1.w) + blo(u2.w)) + (blo(u3.w) + blo(u4.w));
    a7 += (bhi(u1.w) + bhi(u2.w)) + (bhi(u3.w) + bhi(u4.w));
  }
  for (; j < d; ++j) {
    int n1 = csr[s0 + j];
    uint4 u1 = T4[(long)n1 * 16 + lane];
    a0 += blo(u1.x); a1 += bhi(u1.x); a2 += blo(u1.y); a3 += bhi(u1.y);
    a4 += blo(u1.z); a5 += bhi(u1.z); a6 += blo(u1.w); a7 += bhi(u1.w);
  }
  float di = dinv[i];
  float v0 = fmaxf(di * a0 + b0, 0.f);
  float v1 = fmaxf(di * a1 + b1, 0.f);
  float v2 = fmaxf(di * a2 + b2, 0.f);
  float v3 = fmaxf(di * a3 + b3, 0.f);
  float v4 = fmaxf(di * a4 + b4, 0.f);
  float v5 = fmaxf(di * a5 + b5, 0.f);
  float v6 = fmaxf(di * a6 + b6, 0.f);
  float v7 = fmaxf(di * a7 + b7, 0.f);
  uint4 o;
  o.x = pk2(v0, v1); o.y = pk2(v2, v3); o.z = pk2(v4, v5); o.w = pk2(v6, v7);
  outu[(long)i * 16 + lane] = o;
}

// ---------------- graph start offsets from sorted batch ----------------
__global__ void k_starts(const int* __restrict__ batch, int N, int* __restrict__ start) {
  int i = blockIdx.x * blockDim.x + threadIdx.x;
  int stride = gridDim.x * blockDim.x;
  for (; i < N; i += stride) {
    int g = batch[i];
    if (i == 0) {
      start[g] = 0;
    } else if (batch[i - 1] != g) {
      start[g] = i;
    }
  }
}

__global__ void k_fix_starts(int* __restrict__ start, int G, int N) {
  if (blockIdx.x == 0 && threadIdx.x == 0) {
    start[G] = N;
    for (int g = G - 1; g >= 0; --g)
      if (start[g] < 0) start[g] = start[g + 1];
  }
}

// ---------------- parallel mean-pool (batch sorted, h bf16 [N][64]) -------------
__global__ __launch_bounds__(256) void k_pool2(const unsigned* __restrict__ hu,
                                               const int* __restrict__ batch,
                                               float* __restrict__ psum, int N) {
  int t = threadIdx.x;
  int rg = t >> 6;        // row group 0..3
  int lane = t & 63;      // u32 index in row
  long base = (long)blockIdx.x * 64;
  float a0 = 0.f, a1 = 0.f;
  int cur = -1;
#pragma unroll
  for (int j = 0; j < 16; ++j) {
    long r = base + j * 4 + rg;
    if (r >= N) break;
    int g = batch[r];
    if (g != cur) {
      if (cur >= 0) {
        atomicAdd(&psum[cur * HID + lane * 2], a0);
        atomicAdd(&psum[cur * HID + lane * 2 + 1], a1);
        a0 = 0.f; a1 = 0.f;
      }
      cur = g;
    }
    unsigned u = hu[r * 64 + lane];
    a0 += blo(u); a1 += bhi(u);
  }
  if (cur >= 0) {
    atomicAdd(&psum[cur * HID + lane * 2], a0);
    atomicAdd(&psum[cur * HID + lane * 2 + 1], a1);
  }
}

// ---------------- MLP head ----------------
__global__ __launch_bounds__(128) void k_head(const float* __restrict__ psum,
                                              const int* __restrict__ gstart,
                                              const float* __restrict__ fc1w,
                                              const float* __restrict__ fc1b,
                                              const float* __restrict__ fc2w,
                                              const float* __restrict__ fc2b,
                                              float* __restrict__ out, int G) {
  __shared__ float pooled[HID];
  __shared__ float z1[HID];
  int g = blockIdx.x;
  int c = threadIdx.x;
  float cn = fmaxf((float)(gstart[g + 1] - gstart[g]), 1.f);
  pooled[c] = psum[g * HID + c] / cn;
  __syncthreads();
  float a = fc1b[c];
#pragma unroll 8
  for (int k = 0; k < HID; ++k) a += pooled[k] * fc1w[k * HID + c];
  z1[c] = fmaxf(a, 0.f);
  __syncthreads();
  if (c < 16) {
    float o = fc2b[c];
#pragma unroll 8
    for (int k = 0; k < HID; ++k) o += z1[k] * fc2w[k * 16 + c];
    out[g * 16 + c] = o;
  }
}

extern "C" void kernel_launch(void* const* d_in, const int* in_sizes, int n_in,
                              void* d_out, int out_size, void* d_ws, size_t ws_size,
                              hipStream_t stream) {
  const float* x     = (const float*)d_in[0];
  const int*   ei    = (const int*)d_in[1];
  const int*   batch = (const int*)d_in[2];
  const float* w1    = (const float*)d_in[3];
  const float* b1    = (const float*)d_in[4];
  const float* w2    = (const float*)d_in[5];
  const float* b2    = (const float*)d_in[6];
  const float* w3    = (const float*)d_in[7];
  const float* b3    = (const float*)d_in[8];
  const float* fc1w  = (const float*)d_in[9];
  const float* fc1b  = (const float*)d_in[10];
  const float* fc2w  = (const float*)d_in[11];
  const float* fc2b  = (const float*)d_in[12];
  float* out = (float*)d_out;

  const int IN = in_sizes[3] / HID;   // 260
  const int N  = in_sizes[0] / IN;    // 100000
  const int E  = in_sizes[1] / 2;     // 3200000
  const int G  = out_size / 16;       // 64

  const int* srcp = ei;
  const int* dstp = ei + E;

  // ---- workspace carve ----
  char* wsp = (char*)d_ws;
  auto alloc = [&](size_t bytes) {
    char* p = wsp;
    wsp += (bytes + 255) & ~(size_t)255;
    return p;
  };
  int*   deg      = (int*)alloc((size_t)N * 4);
  int*   rowstart = (int*)alloc((size_t)N * 4);
  int*   bsum     = (int*)alloc(1024 * 4);
  int*   boff     = (int*)alloc(1024 * 4);
  int*   bhist    = (int*)alloc(NB * 4);
  int*   bstart   = (int*)alloc((NB + 1) * 4);
  int*   gcur     = (int*)alloc(NB * 4);
  int*   gstart   = (int*)alloc((size_t)(G + 1) * 4);
  float* dinv     = (float*)alloc((size_t)N * 4);
  float* psum     = (float*)alloc((size_t)G * HID * 4);
  unsigned* Wt1   = (unsigned*)alloc(128 * 144 * 4);
  unsigned* Wt2   = (unsigned*)alloc(128 * 64 * 4);
  unsigned* Wt3   = (unsigned*)alloc(128 * 64 * 4);
  int*   csr      = (int*)alloc((size_t)E * 4);
  unsigned* bufA  = (unsigned*)alloc((size_t)N * 64 * 4);  // bf16 [N][128] packed
  unsigned* bufB  = (unsigned*)alloc((size_t)N * 64 * 4);  // bf16 [N][128] packed
  // binned edge array (E x 8B = 25.6MB) aliases bufA; consumed before first GEMM.
  unsigned long long* binned = (unsigned long long*)bufA;

  // ---- init (fused) + weight prep (fused) ----
  k_init<<<32, 256, 0, stream>>>(psum, gstart, bhist, G);
  k_prep_w3<<<136, 256, 0, stream>>>(w1, w2, w3, Wt1, Wt2, Wt3, IN);

  // ---- binned CSR build ----
  k_hist<<<512, 256, 0, stream>>>(dstp, E, N, bhist);
  k_bscan<<<1, 1, 0, stream>>>(bhist, bstart, gcur, E);
  k_scatter<<<1024, 256, 0, stream>>>(srcp, dstp, E, N, binned, gcur);
  k_bdeg<<<NB, 256, 0, stream>>>(binned, bstart, N, deg, dinv);

  int nb = (N + SCAN_CHUNK - 1) / SCAN_CHUNK;
  k_scan_block_sums<<<nb, 256, 0, stream>>>(deg, N, bsum);
  k_scan_offsets<<<1, 1, 0, stream>>>(bsum, nb, boff);
  k_scan_write<<<nb, 256, 0, stream>>>(deg, N, boff, rowstart);
  k_place<<<NB, 256, 0, stream>>>(binned, bstart, rowstart, N, csr);

  // ---- graph boundaries ----
  k_starts<<<256, 256, 0, stream>>>(batch, N, gstart);
  k_fix_starts<<<1, 1, 0, stream>>>(gstart, G, N);

  // ---- 3 GCN layers: MFMA GEMM (epilogue scales by dinv, packs bf16) + agg ----
  int gblocks = (N + 127) / 128;
  int ablocks = (N + 15) / 16;
  k_gemm1_mf<<<gblocks, 256, 0, stream>>>(x, Wt1, dinv, bufA, N, IN);
  k_agg<<<ablocks, 256, 0, stream>>>((const uint4*)bufA, dinv, rowstart, deg, csr, b1,
                                     (uint4*)bufB, N);

  k_gemm_mf<<<gblocks, 256, 0, stream>>>(bufB, Wt2, dinv, bufA, N);
  k_agg<<<ablocks, 256, 0, stream>>>((const uint4*)bufA, dinv, rowstart, deg, csr, b2,
                                     (uint4*)bufB, N);

  k_gemm_mf<<<gblocks, 256, 0, stream>>>(bufB, Wt3, dinv, bufA, N);
  k_agg<<<ablocks, 256, 0, stream>>>((const uint4*)bufA, dinv, rowstart, deg, csr, b3,
                                     (uint4*)bufB, N);

  // ---- pool + head ----
  int pblocks = (N + 63) / 64;
  k_pool2<<<pblocks, 256, 0, stream>>>(bufB, batch, psum, N);
  k_head<<<G, 128, 0, stream>>>(psum, gstart, fc1w, fc1b, fc2w, fc2b, out, G);
}

// Round 11
// 609.504 us; speedup vs baseline: 1.9052x; 1.0095x over previous
//
#include <hip/hip_runtime.h>

#define HID 128
#define SCAN_CHUNK 1024

// binned CSR build params
#define NB 256
#define BW 400
#define DEPTH 24
#define CH 2048

typedef __attribute__((ext_vector_type(8))) short bf16x8;
typedef __attribute__((ext_vector_type(4))) float f32x4;

// ---------------- bf16 helpers (RNE pack, shift unpack) ----------------
__device__ inline float blo(unsigned u) { return __uint_as_float(u << 16); }
__device__ inline float bhi(unsigned u) { return __uint_as_float(u & 0xffff0000u); }
__device__ inline unsigned rne16(float x) {
  unsigned u = __float_as_uint(x);
  return (u + 0x7fffu + ((u >> 16) & 1u)) >> 16;
}
__device__ inline unsigned pk2(float a, float b) { return (rne16(b) << 16) | rne16(a); }

// ---------------- fused init: psum=0, gstart=-1, bhist=0 ----------------
__global__ void k_init(float* __restrict__ psum, int* __restrict__ gstart,
                       int* __restrict__ bhist, int G) {
  int i = blockIdx.x * 256 + threadIdx.x;
  if (i < G * HID) psum[i] = 0.f;
  if (i <= G) gstart[i] = -1;
  if (i < NB) bhist[i] = 0;
}

// ---------------- fused weight transpose + bf16 pack (all 3 layers) -------------
__device__ inline void prep_one(const float* __restrict__ W, unsigned* __restrict__ Wt,
                                int K, int KP2, int b) {
  int idx = b * 256 + threadIdx.x;
  if (idx >= 128 * KP2) return;
  int c = idx / KP2, kk = idx - c * KP2;
  int k0 = kk * 2, k1 = k0 + 1;
  float v0 = (k0 < K) ? W[(long)k0 * 128 + c] : 0.f;
  float v1 = (k1 < K) ? W[(long)k1 * 128 + c] : 0.f;
  Wt[idx] = pk2(v0, v1);
}

__global__ void k_prep_w3(const float* __restrict__ w1, const float* __restrict__ w2,
                          const float* __restrict__ w3, unsigned* __restrict__ Wt1,
                          unsigned* __restrict__ Wt2, unsigned* __restrict__ Wt3,
                          int IN) {
  int b = blockIdx.x;
  if (b < 72) prep_one(w1, Wt1, IN, 144, b);
  else if (b < 104) prep_one(w2, Wt2, 128, 64, b - 72);
  else prep_one(w3, Wt3, 128, 64, b - 104);
}

// ---------------- bucket histogram (LDS-staged) ----------------
__global__ __launch_bounds__(256) void k_hist(const int* __restrict__ dst, int E, int N,
                                              int* __restrict__ bhist) {
  __shared__ int h[NB];
  int t = threadIdx.x;
  h[t] = 0;
  __syncthreads();
  int i = blockIdx.x * blockDim.x + t;
  int stride = gridDim.x * blockDim.x;
  for (; i < E; i += stride) {
    int b = (int)(((long long)dst[i] * NB) / N);
    atomicAdd(&h[b], 1);
  }
  __syncthreads();
  if (h[t]) atomicAdd(&bhist[t], h[t]);
}

// ---------------- parallel exclusive scan of bhist -> bstart, gcur ----------------
__global__ __launch_bounds__(NB) void k_bscan(const int* __restrict__ bhist,
                                              int* __restrict__ bstart,
                                              int* __restrict__ gcur, int E) {
  __shared__ int sh[NB];
  int t = threadIdx.x;
  int v = bhist[t];
  sh[t] = v;
  __syncthreads();
  for (int off = 1; off < NB; off <<= 1) {
    int x = (t >= off) ? sh[t - off] : 0;
    __syncthreads();
    sh[t] += x;
    __syncthreads();
  }
  int excl = sh[t] - v;
  bstart[t] = excl;
  gcur[t] = excl;
  if (t == NB - 1) bstart[NB] = sh[t];  // == E
}

// ---------------- LDS-staged scatter into bucket-major order ----------------
__global__ __launch_bounds__(256) void k_scatter(const int* __restrict__ src,
                                                 const int* __restrict__ dst,
                                                 int E, int N,
                                                 unsigned long long* __restrict__ binned,
                                                 int* __restrict__ gcur) {
  __shared__ unsigned long long buf[NB][DEPTH]; // 48 KB
  __shared__ int cnt[NB];
  int t = threadIdx.x;
  long cover = (long)gridDim.x * CH;
  int nround = (int)((E + cover - 1) / cover);
  for (int r = 0; r < nround; ++r) {
    cnt[t] = 0;
    __syncthreads();
    long base = (long)r * cover + (long)blockIdx.x * CH;
#pragma unroll
    for (int k = 0; k < CH / 256; ++k) {
      long i = base + k * 256 + t;
      if (i < E) {
        int s = src[i], d = dst[i];
        int b = (int)(((long long)d * NB) / N);
        unsigned long long pack =
            ((unsigned long long)(unsigned)d << 32) | (unsigned)s;
        int slot = atomicAdd(&cnt[b], 1);
        if (slot < DEPTH) buf[b][slot] = pack;
        else { int g = atomicAdd(&gcur[b], 1); binned[g] = pack; } // rare spill
      }
    }
    __syncthreads();
    {
      int c = cnt[t];
      if (c > DEPTH) c = DEPTH;
      if (c > 0) {
        int g = atomicAdd(&gcur[t], c);
        for (int k = 0; k < c; ++k) binned[g + k] = buf[t][k];
      }
    }
    __syncthreads();
  }
}

// ---------------- per-bucket degree histogram + fused dinv ----------------
__global__ __launch_bounds__(256) void k_bdeg(const unsigned long long* __restrict__ binned,
                                              const int* __restrict__ bstart, int N,
                                              int* __restrict__ deg,
                                              float* __restrict__ dinv) {
  __shared__ int hist[BW];
  int b = blockIdx.x;
  int t = threadIdx.x;
  int d0 = (int)(((long long)b * N + NB - 1) / NB);
  int d1 = (int)(((long long)(b + 1) * N + NB - 1) / NB);
  if (d1 > N) d1 = N;
  int W = d1 - d0;
  for (int w = t; w < W; w += 256) hist[w] = 0;
  __syncthreads();
  int s = bstart[b], e = bstart[b + 1];
  for (int i = s + t; i < e; i += 256) {
    int d = (int)(binned[i] >> 32);
    atomicAdd(&hist[d - d0], 1);
  }
  __syncthreads();
  for (int w = t; w < W; w += 256) {
    int dv = hist[w];
    deg[d0 + w] = dv;
    dinv[d0 + w] = rsqrtf((float)(dv + 1)); // +1 = self loop
  }
}

// ---------------- exclusive scan of deg -> rowstart ----------------
__global__ void k_scan_block_sums(const int* __restrict__ deg, int N, int* __restrict__ bsum) {
  __shared__ int sh[256];
  int base = blockIdx.x * SCAN_CHUNK;
  int t = threadIdx.x;
  int s = 0;
#pragma unroll
  for (int j = 0; j < 4; ++j) {
    int idx = base + t * 4 + j;
    if (idx < N) s += deg[idx];
  }
  sh[t] = s;
  __syncthreads();
  for (int off = 128; off > 0; off >>= 1) {
    if (t < off) sh[t] += sh[t + off];
    __syncthreads();
  }
  if (t == 0) bsum[blockIdx.x] = sh[0];
}

// parallel exclusive scan of block sums (nb <= 256)
__global__ __launch_bounds__(256) void k_scan_offsets(const int* __restrict__ bsum, int nb,
                                                      int* __restrict__ boff) {
  __shared__ int sh[256];
  int t = threadIdx.x;
  int v = (t < nb) ? bsum[t] : 0;
  sh[t] = v;
  __syncthreads();
  for (int off = 1; off < 256; off <<= 1) {
    int x = (t >= off) ? sh[t - off] : 0;
    __syncthreads();
    sh[t] += x;
    __syncthreads();
  }
  if (t < nb) boff[t] = sh[t] - v;
}

__global__ void k_scan_write(const int* __restrict__ deg, int N,
                             const int* __restrict__ boff, int* __restrict__ rowstart) {
  __shared__ int sh[256];
  int base = blockIdx.x * SCAN_CHUNK;
  int t = threadIdx.x;
  int v[4];
  int s = 0;
#pragma unroll
  for (int j = 0; j < 4; ++j) {
    int idx = base + t * 4 + j;
    v[j] = (idx < N) ? deg[idx] : 0;
    s += v[j];
  }
  sh[t] = s;
  __syncthreads();
  for (int off = 1; off < 256; off <<= 1) {
    int x = 0;
    if (t >= off) x = sh[t - off];
    __syncthreads();
    sh[t] += x;
    __syncthreads();
  }
  int excl = sh[t] - s;
  int run = boff[blockIdx.x] + excl;
#pragma unroll
  for (int j = 0; j < 4; ++j) {
    int idx = base + t * 4 + j;
    if (idx < N) rowstart[idx] = run;
    run += v[j];
  }
}

// ---------------- per-bucket CSR placement with LDS cursors ----------------
__global__ __launch_bounds__(256) void k_place(const unsigned long long* __restrict__ binned,
                                               const int* __restrict__ bstart,
                                               const int* __restrict__ rowstart, int N,
                                               int* __restrict__ csr) {
  __shared__ int cur[BW];
  int b = blockIdx.x;
  int t = threadIdx.x;
  int d0 = (int)(((long long)b * N + NB - 1) / NB);
  int d1 = (int)(((long long)(b + 1) * N + NB - 1) / NB);
  if (d1 > N) d1 = N;
  int W = d1 - d0;
  for (int w = t; w < W; w += 256) cur[w] = 0;
  __syncthreads();
  int s = bstart[b], e = bstart[b + 1];
  for (int i = s + t; i < e; i += 256) {
    unsigned long long p = binned[i];
    int d = (int)(p >> 32);
    int sn = (int)(p & 0xffffffffu);
    int pos = rowstart[d] + atomicAdd(&cur[d - d0], 1);
    csr[pos] = sn;
  }
}

// ============ MFMA GEMM, layers 2/3: Cbf16 = dinv(row)*(Abf16[N][128] @ W[128][128]) ==
__global__ __launch_bounds__(256) void k_gemm_mf(const unsigned* __restrict__ A,
                                                 const unsigned* __restrict__ Wt,
                                                 const float* __restrict__ dscale,
                                                 unsigned* __restrict__ Cu, int N) {
  int t = threadIdx.x;
  int w = t >> 6;
  int l = t & 63;
  int lr = l & 15;
  int kg = l >> 4;
  int wr0 = blockIdx.x * 128 + w * 32;

  f32x4 acc[2][8];
#pragma unroll
  for (int rt = 0; rt < 2; ++rt)
#pragma unroll
    for (int f = 0; f < 8; ++f) acc[rt][f] = (f32x4){0.f, 0.f, 0.f, 0.f};

  int r0 = wr0 + lr, r1 = wr0 + 16 + lr;
#pragma unroll
  for (int kt = 0; kt < 4; ++kt) {
    int ko = kt * 16 + kg * 4;
    bf16x8 a0 = {}, a1 = {};
    if (r0 < N) a0 = *(const bf16x8*)&A[(long)r0 * 64 + ko];
    if (r1 < N) a1 = *(const bf16x8*)&A[(long)r1 * 64 + ko];
#pragma unroll
    for (int f = 0; f < 8; ++f) {
      bf16x8 b = *(const bf16x8*)&Wt[(f * 16 + lr) * 64 + ko];
      acc[0][f] = __builtin_amdgcn_mfma_f32_16x16x32_bf16(a0, b, acc[0][f], 0, 0, 0);
      acc[1][f] = __builtin_amdgcn_mfma_f32_16x16x32_bf16(a1, b, acc[1][f], 0, 0, 0);
    }
  }
#pragma unroll
  for (int rt = 0; rt < 2; ++rt) {
#pragma unroll
    for (int reg = 0; reg < 4; ++reg) {
      int row = wr0 + rt * 16 + kg * 4 + reg;
      float ds = (row < N) ? dscale[row] : 0.f;
#pragma unroll
      for (int f = 0; f < 8; ++f) {
        float v = acc[rt][f][reg] * ds;
        float pv = __shfl_xor(v, 1);
        if (!(l & 1) && row < N)
          Cu[(long)row * 64 + ((f * 16 + lr) >> 1)] = pk2(v, pv);
      }
    }
  }
}

// ============ MFMA GEMM, layer 1: x f32 -> bf16 in-flight ============
__global__ __launch_bounds__(256) void k_gemm1_mf(const float* __restrict__ X,
                                                  const unsigned* __restrict__ Wt,
                                                  const float* __restrict__ dscale,
                                                  unsigned* __restrict__ Cu, int N, int K) {
  int t = threadIdx.x;
  int w = t >> 6;
  int l = t & 63;
  int lr = l & 15;
  int kg = l >> 4;
  int wr0 = blockIdx.x * 128 + w * 32;

  f32x4 acc[2][8];
#pragma unroll
  for (int rt = 0; rt < 2; ++rt)
#pragma unroll
    for (int f = 0; f < 8; ++f) acc[rt][f] = (f32x4){0.f, 0.f, 0.f, 0.f};

  int r0 = wr0 + lr, r1 = wr0 + 16 + lr;
  int nkt = (K + 31) / 32;  // 9 for K=260
  for (int kt = 0; kt < nkt; ++kt) {
    int kb = kt * 32 + kg * 8;
    bf16x8 a0 = {}, a1 = {};
    if (kb + 7 < K) {
      if (r0 < N) {
        const float* p = &X[(long)r0 * K + kb];
        float4 u = *(const float4*)p, v = *(const float4*)(p + 4);
        union { uint4 q; bf16x8 b; } cv;
        cv.q.x = pk2(u.x, u.y); cv.q.y = pk2(u.z, u.w);
        cv.q.z = pk2(v.x, v.y); cv.q.w = pk2(v.z, v.w);
        a0 = cv.b;
      }
      if (r1 < N) {
        const float* p = &X[(long)r1 * K + kb];
        float4 u = *(const float4*)p, v = *(const float4*)(p + 4);
        union { uint4 q; bf16x8 b; } cv;
        cv.q.x = pk2(u.x, u.y); cv.q.y = pk2(u.z, u.w);
        cv.q.z = pk2(v.x, v.y); cv.q.w = pk2(v.z, v.w);
        a1 = cv.b;
      }
    } else if (kb < K) {  // partial tail (k=256..259)
      float t0[8], t1[8];
#pragma unroll
      for (int j = 0; j < 8; ++j) {
        int k = kb + j;
        t0[j] = (r0 < N && k < K) ? X[(long)r0 * K + k] : 0.f;
        t1[j] = (r1 < N && k < K) ? X[(long)r1 * K + k] : 0.f;
      }
      union { uint4 q; bf16x8 b; } c0, c1;
      c0.q.x = pk2(t0[0], t0[1]); c0.q.y = pk2(t0[2], t0[3]);
      c0.q.z = pk2(t0[4], t0[5]); c0.q.w = pk2(t0[6], t0[7]);
      c1.q.x = pk2(t1[0], t1[1]); c1.q.y = pk2(t1[2], t1[3]);
      c1.q.z = pk2(t1[4], t1[5]); c1.q.w = pk2(t1[6], t1[7]);
      a0 = c0.b; a1 = c1.b;
    }
    int ko = kt * 16 + kg * 4;
#pragma unroll
    for (int f = 0; f < 8; ++f) {
      bf16x8 b = *(const bf16x8*)&Wt[(f * 16 + lr) * 144 + ko];
      acc[0][f] = __builtin_amdgcn_mfma_f32_16x16x32_bf16(a0, b, acc[0][f], 0, 0, 0);
      acc[1][f] = __builtin_amdgcn_mfma_f32_16x16x32_bf16(a1, b, acc[1][f], 0, 0, 0);
    }
  }
#pragma unroll
  for (int rt = 0; rt < 2; ++rt) {
#pragma unroll
    for (int reg = 0; reg < 4; ++reg) {
      int row = wr0 + rt * 16 + kg * 4 + reg;
      float ds = (row < N) ? dscale[row] : 0.f;
#pragma unroll
      for (int f = 0; f < 8; ++f) {
        float v = acc[rt][f][reg] * ds;
        float pv = __shfl_xor(v, 1);
        if (!(l & 1) && row < N)
          Cu[(long)row * 64 + ((f * 16 + lr) >> 1)] = pk2(v, pv);
      }
    }
  }
}

// ---------------- pull aggregation v4: 16 lanes x uint4 per node ----------------
__global__ __launch_bounds__(256) void k_agg(const uint4* __restrict__ T4,  // [N][16]
                                             const float* __restrict__ dinv,
                                             const int* __restrict__ rowstart,
                                             const int* __restrict__ deg,
                                             const int* __restrict__ csr,
                                             const float* __restrict__ bias,
                                             uint4* __restrict__ outu,      // [N][16]
                                             int N) {
  int t = threadIdx.x;
  int grp = t >> 4;        // node slot 0..15
  int lane = t & 15;       // uint4 slot in row (8 channels)
  int i = blockIdx.x * 16 + grp;
  if (i >= N) return;

  int c0 = lane * 8;
  float b0 = bias[c0 + 0], b1 = bias[c0 + 1], b2 = bias[c0 + 2], b3 = bias[c0 + 3];
  float b4 = bias[c0 + 4], b5 = bias[c0 + 5], b6 = bias[c0 + 6], b7 = bias[c0 + 7];

  uint4 su = T4[(long)i * 16 + lane];  // self-loop (pre-scaled)
  float a0 = blo(su.x), a1 = bhi(su.x), a2 = blo(su.y), a3 = bhi(su.y);
  float a4 = blo(su.z), a5 = bhi(su.z), a6 = blo(su.w), a7 = bhi(su.w);

  int s0 = rowstart[i];
  int d = deg[i];
  int j = 0;
  for (; j + 3 < d; j += 4) {
    int n1 = csr[s0 + j];
    int n2 = csr[s0 + j + 1];
    int n3 = csr[s0 + j + 2];
    int n4 = csr[s0 + j + 3];
    uint4 u1 = T4[(long)n1 * 16 + lane];
    uint4 u2 = T4[(long)n2 * 16 + lane];
    uint4 u3 = T4[(long)n3 * 16 + lane];
    uint4 u4 = T4[(long)n4 * 16 + lane];
    a0 += (blo(u1.x) + blo(u2.x)) + (blo(u3.x) + blo(u4.x));
    a1 += (bhi(u1.x) + bhi(u2.x)) + (bhi(u3.x) + bhi(u4.x));
    a2 += (blo(u1.y) + blo(u2.y)) + (blo(u3.y) + blo(u4.y));
    a3 += (bhi(u1.y) + bhi(u2.y)) + (bhi(u3.y) + bhi(u4.y));
    a4 += (blo(u1.z) + blo(u2.z)) + (blo(u3.z) + blo(u4.z));
    a5 += (bhi(u1.z) + bhi(u2.z)) + (bhi(u3.z) + bhi(u4.z));
    a6 += (blo(u1.w) + blo(u2.w)) + (blo(u3.w) + blo(u4.w));
    a7 += (bhi(u1.w) + bhi(u2.w)) + (bhi(u3.w) + bhi(u4.w));
  }
  for (; j < d; ++j) {
    int n1 = csr[s0 + j];
    uint4 u1 = T4[(long)n1 * 16 + lane];
    a0 += blo(u1.x); a1 += bhi(u1.x); a2 += blo(u1.y); a3 += bhi(u1.y);
    a4 += blo(u1.z); a5 += bhi(u1.z); a6 += blo(u1.w); a7 += bhi(u1.w);
  }
  float di = dinv[i];
  float v0 = fmaxf(di * a0 + b0, 0.f);
  float v1 = fmaxf(di * a1 + b1, 0.f);
  float v2 = fmaxf(di * a2 + b2, 0.f);
  float v3 = fmaxf(di * a3 + b3, 0.f);
  float v4 = fmaxf(di * a4 + b4, 0.f);
  float v5 = fmaxf(di * a5 + b5, 0.f);
  float v6 = fmaxf(di * a6 + b6, 0.f);
  float v7 = fmaxf(di * a7 + b7, 0.f);
  uint4 o;
  o.x = pk2(v0, v1); o.y = pk2(v2, v3); o.z = pk2(v4, v5); o.w = pk2(v6, v7);
  outu[(long)i * 16 + lane] = o;
}

// ---------------- graph start offsets from sorted batch ----------------
__global__ void k_starts(const int* __restrict__ batch, int N, int* __restrict__ start) {
  int i = blockIdx.x * blockDim.x + threadIdx.x;
  int stride = gridDim.x * blockDim.x;
  for (; i < N; i += stride) {
    int g = batch[i];
    if (i == 0) {
      start[g] = 0;
    } else if (batch[i - 1] != g) {
      start[g] = i;
    }
  }
}

// parallel back-fill of empty graphs via reverse min-scan (starts are monotone).
// result[g] = min over g'>=g of (start[g'] if defined, else N). G <= 256.
__global__ __launch_bounds__(256) void k_fix_starts(int* __restrict__ start, int G, int N) {
  __shared__ int sh[256];
  int t = threadIdx.x;
  int v = (t < G) ? start[t] : N;
  if (v < 0) v = N;
  sh[t] = v;
  __syncthreads();
  for (int off = 1; off < 256; off <<= 1) {
    int x = (t + off < 256) ? sh[t + off] : N;
    int nv = min(sh[t], x);
    __syncthreads();
    sh[t] = nv;
    __syncthreads();
  }
  if (t < G) start[t] = sh[t];
  if (t == 0) start[G] = N;
}

// ---------------- parallel mean-pool (batch sorted, h bf16 [N][64]) -------------
__global__ __launch_bounds__(256) void k_pool2(const unsigned* __restrict__ hu,
                                               const int* __restrict__ batch,
                                               float* __restrict__ psum, int N) {
  int t = threadIdx.x;
  int rg = t >> 6;        // row group 0..3
  int lane = t & 63;      // u32 index in row
  long base = (long)blockIdx.x * 64;
  float a0 = 0.f, a1 = 0.f;
  int cur = -1;
#pragma unroll
  for (int j = 0; j < 16; ++j) {
    long r = base + j * 4 + rg;
    if (r >= N) break;
    int g = batch[r];
    if (g != cur) {
      if (cur >= 0) {
        atomicAdd(&psum[cur * HID + lane * 2], a0);
        atomicAdd(&psum[cur * HID + lane * 2 + 1], a1);
        a0 = 0.f; a1 = 0.f;
      }
      cur = g;
    }
    unsigned u = hu[r * 64 + lane];
    a0 += blo(u); a1 += bhi(u);
  }
  if (cur >= 0) {
    atomicAdd(&psum[cur * HID + lane * 2], a0);
    atomicAdd(&psum[cur * HID + lane * 2 + 1], a1);
  }
}

// ---------------- MLP head ----------------
__global__ __launch_bounds__(128) void k_head(const float* __restrict__ psum,
                                              const int* __restrict__ gstart,
                                              const float* __restrict__ fc1w,
                                              const float* __restrict__ fc1b,
                                              const float* __restrict__ fc2w,
                                              const float* __restrict__ fc2b,
                                              float* __restrict__ out, int G) {
  __shared__ float pooled[HID];
  __shared__ float z1[HID];
  int g = blockIdx.x;
  int c = threadIdx.x;
  float cn = fmaxf((float)(gstart[g + 1] - gstart[g]), 1.f);
  pooled[c] = psum[g * HID + c] / cn;
  __syncthreads();
  float a = fc1b[c];
#pragma unroll 8
  for (int k = 0; k < HID; ++k) a += pooled[k] * fc1w[k * HID + c];
  z1[c] = fmaxf(a, 0.f);
  __syncthreads();
  if (c < 16) {
    float o = fc2b[c];
#pragma unroll 8
    for (int k = 0; k < HID; ++k) o += z1[k] * fc2w[k * 16 + c];
    out[g * 16 + c] = o;
  }
}

extern "C" void kernel_launch(void* const* d_in, const int* in_sizes, int n_in,
                              void* d_out, int out_size, void* d_ws, size_t ws_size,
                              hipStream_t stream) {
  const float* x     = (const float*)d_in[0];
  const int*   ei    = (const int*)d_in[1];
  const int*   batch = (const int*)d_in[2];
  const float* w1    = (const float*)d_in[3];
  const float* b1    = (const float*)d_in[4];
  const float* w2    = (const float*)d_in[5];
  const float* b2    = (const float*)d_in[6];
  const float* w3    = (const float*)d_in[7];
  const float* b3    = (const float*)d_in[8];
  const float* fc1w  = (const float*)d_in[9];
  const float* fc1b  = (const float*)d_in[10];
  const float* fc2w  = (const float*)d_in[11];
  const float* fc2b  = (const float*)d_in[12];
  float* out = (float*)d_out;

  const int IN = in_sizes[3] / HID;   // 260
  const int N  = in_sizes[0] / IN;    // 100000
  const int E  = in_sizes[1] / 2;     // 3200000
  const int G  = out_size / 16;       // 64

  const int* srcp = ei;
  const int* dstp = ei + E;

  // ---- workspace carve ----
  char* wsp = (char*)d_ws;
  auto alloc = [&](size_t bytes) {
    char* p = wsp;
    wsp += (bytes + 255) & ~(size_t)255;
    return p;
  };
  int*   deg      = (int*)alloc((size_t)N * 4);
  int*   rowstart = (int*)alloc((size_t)N * 4);
  int*   bsum     = (int*)alloc(1024 * 4);
  int*   boff     = (int*)alloc(1024 * 4);
  int*   bhist    = (int*)alloc(NB * 4);
  int*   bstart   = (int*)alloc((NB + 1) * 4);
  int*   gcur     = (int*)alloc(NB * 4);
  int*   gstart   = (int*)alloc((size_t)(G + 1) * 4);
  float* dinv     = (float*)alloc((size_t)N * 4);
  float* psum     = (float*)alloc((size_t)G * HID * 4);
  unsigned* Wt1   = (unsigned*)alloc(128 * 144 * 4);
  unsigned* Wt2   = (unsigned*)alloc(128 * 64 * 4);
  unsigned* Wt3   = (unsigned*)alloc(128 * 64 * 4);
  int*   csr      = (int*)alloc((size_t)E * 4);
  unsigned* bufA  = (unsigned*)alloc((size_t)N * 64 * 4);  // bf16 [N][128] packed
  unsigned* bufB  = (unsigned*)alloc((size_t)N * 64 * 4);  // bf16 [N][128] packed
  // binned edge array (E x 8B = 25.6MB) aliases bufA; consumed before first GEMM.
  unsigned long long* binned = (unsigned long long*)bufA;

  // ---- init (fused) + weight prep (fused) ----
  k_init<<<32, 256, 0, stream>>>(psum, gstart, bhist, G);
  k_prep_w3<<<136, 256, 0, stream>>>(w1, w2, w3, Wt1, Wt2, Wt3, IN);

  // ---- binned CSR build ----
  k_hist<<<512, 256, 0, stream>>>(dstp, E, N, bhist);
  k_bscan<<<1, NB, 0, stream>>>(bhist, bstart, gcur, E);
  k_scatter<<<782, 256, 0, stream>>>(srcp, dstp, E, N, binned, gcur);
  k_bdeg<<<NB, 256, 0, stream>>>(binned, bstart, N, deg, dinv);

  int nb = (N + SCAN_CHUNK - 1) / SCAN_CHUNK;
  k_scan_block_sums<<<nb, 256, 0, stream>>>(deg, N, bsum);
  k_scan_offsets<<<1, 256, 0, stream>>>(bsum, nb, boff);
  k_scan_write<<<nb, 256, 0, stream>>>(deg, N, boff, rowstart);
  k_place<<<NB, 256, 0, stream>>>(binned, bstart, rowstart, N, csr);

  // ---- graph boundaries ----
  k_starts<<<256, 256, 0, stream>>>(batch, N, gstart);
  k_fix_starts<<<1, 256, 0, stream>>>(gstart, G, N);

  // ---- 3 GCN layers: MFMA GEMM (epilogue scales by dinv, packs bf16) + agg ----
  int gblocks = (N + 127) / 128;
  int ablocks = (N + 15) / 16;
  k_gemm1_mf<<<gblocks, 256, 0, stream>>>(x, Wt1, dinv, bufA, N, IN);
  k_agg<<<ablocks, 256, 0, stream>>>((const uint4*)bufA, dinv, rowstart, deg, csr, b1,
                                     (uint4*)bufB, N);

  k_gemm_mf<<<gblocks, 256, 0, stream>>>(bufB, Wt2, dinv, bufA, N);
  k_agg<<<ablocks, 256, 0, stream>>>((const uint4*)bufA, dinv, rowstart, deg, csr, b2,
                                     (uint4*)bufB, N);

  k_gemm_mf<<<gblocks, 256, 0, stream>>>(bufB, Wt3, dinv, bufA, N);
  k_agg<<<ablocks, 256, 0, stream>>>((const uint4*)bufA, dinv, rowstart, deg, csr, b3,
                                     (uint4*)bufB, N);

  // ---- pool + head ----
  int pblocks = (N + 63) / 64;
  k_pool2<<<pblocks, 256, 0, stream>>>(bufB, batch, psum, N);
  k_head<<<G, 128, 0, stream>>>(psum, gstart, fc1w, fc1b, fc2w, fc2b, out, G);
}

// Round 12
// 580.253 us; speedup vs baseline: 2.0012x; 1.0504x over previous
//
#include <hip/hip_runtime.h>

#define HID 128

// binned CSR build params
#define NB 256
#define BW 400
#define DEPTH 24
#define CH 2048

typedef __attribute__((ext_vector_type(8))) short bf16x8;
typedef __attribute__((ext_vector_type(4))) float f32x4;

// ---------------- bf16 helpers (RNE pack, shift unpack) ----------------
__device__ inline float blo(unsigned u) { return __uint_as_float(u << 16); }
__device__ inline float bhi(unsigned u) { return __uint_as_float(u & 0xffff0000u); }
__device__ inline unsigned rne16(float x) {
  unsigned u = __float_as_uint(x);
  return (u + 0x7fffu + ((u >> 16) & 1u)) >> 16;
}
__device__ inline unsigned pk2(float a, float b) { return (rne16(b) << 16) | rne16(a); }

// ---------------- fused: weight transpose/pack + state init ----------------
__device__ inline void prep_one(const float* __restrict__ W, unsigned* __restrict__ Wt,
                                int K, int KP2, int b) {
  int idx = b * 256 + threadIdx.x;
  if (idx >= 128 * KP2) return;
  int c = idx / KP2, kk = idx - c * KP2;
  int k0 = kk * 2, k1 = k0 + 1;
  float v0 = (k0 < K) ? W[(long)k0 * 128 + c] : 0.f;
  float v1 = (k1 < K) ? W[(long)k1 * 128 + c] : 0.f;
  Wt[idx] = pk2(v0, v1);
}

__global__ void k_prep_init(const float* __restrict__ w1, const float* __restrict__ w2,
                            const float* __restrict__ w3, unsigned* __restrict__ Wt1,
                            unsigned* __restrict__ Wt2, unsigned* __restrict__ Wt3,
                            float* __restrict__ psum, int* __restrict__ gstart,
                            int* __restrict__ bhist, int IN, int G) {
  int b = blockIdx.x;
  if (b < 72) prep_one(w1, Wt1, IN, 144, b);
  else if (b < 104) prep_one(w2, Wt2, 128, 64, b - 72);
  else prep_one(w3, Wt3, 128, 64, b - 104);
  if (b < 32) {
    int i = b * 256 + threadIdx.x;
    if (i < G * HID) psum[i] = 0.f;
    if (i <= G) gstart[i] = -1;
    if (i < NB) bhist[i] = 0;
  }
}

// ---------------- bucket histogram (LDS-staged) ----------------
__global__ __launch_bounds__(256) void k_hist(const int* __restrict__ dst, int E, int N,
                                              int* __restrict__ bhist) {
  __shared__ int h[NB];
  int t = threadIdx.x;
  h[t] = 0;
  __syncthreads();
  int i = blockIdx.x * blockDim.x + t;
  int stride = gridDim.x * blockDim.x;
  for (; i < E; i += stride) {
    int b = (int)(((long long)dst[i] * NB) / N);
    atomicAdd(&h[b], 1);
  }
  __syncthreads();
  if (h[t]) atomicAdd(&bhist[t], h[t]);
}

// ---------------- parallel exclusive scan of bhist -> bstart, gcur ----------------
__global__ __launch_bounds__(NB) void k_bscan(const int* __restrict__ bhist,
                                              int* __restrict__ bstart,
                                              int* __restrict__ gcur, int E) {
  __shared__ int sh[NB];
  int t = threadIdx.x;
  int v = bhist[t];
  sh[t] = v;
  __syncthreads();
  for (int off = 1; off < NB; off <<= 1) {
    int x = (t >= off) ? sh[t - off] : 0;
    __syncthreads();
    sh[t] += x;
    __syncthreads();
  }
  int excl = sh[t] - v;
  bstart[t] = excl;
  gcur[t] = excl;
  if (t == NB - 1) bstart[NB] = sh[t];  // == E
}

// ---------------- LDS-staged scatter into bucket-major order (u32 packed) --------
// pack = (d_local << 17) | src   (d_local < 512, src < 131072)
__global__ __launch_bounds__(256) void k_scatter(const int* __restrict__ src,
                                                 const int* __restrict__ dst,
                                                 int E, int N,
                                                 unsigned* __restrict__ binned,
                                                 int* __restrict__ gcur) {
  __shared__ unsigned buf[NB][DEPTH]; // 24 KB
  __shared__ int cnt[NB];
  int t = threadIdx.x;
  long cover = (long)gridDim.x * CH;
  int nround = (int)((E + cover - 1) / cover);
  for (int r = 0; r < nround; ++r) {
    cnt[t] = 0;
    __syncthreads();
    long base = (long)r * cover + (long)blockIdx.x * CH;
#pragma unroll
    for (int k = 0; k < CH / 256; ++k) {
      long i = base + k * 256 + t;
      if (i < E) {
        int s = src[i], d = dst[i];
        int b = (int)(((long long)d * NB) / N);
        int d0 = (int)(((long long)b * N + NB - 1) / NB);
        unsigned pack = ((unsigned)(d - d0) << 17) | (unsigned)s;
        int slot = atomicAdd(&cnt[b], 1);
        if (slot < DEPTH) buf[b][slot] = pack;
        else { int g = atomicAdd(&gcur[b], 1); binned[g] = pack; } // rare spill
      }
    }
    __syncthreads();
    {
      int c = cnt[t];
      if (c > DEPTH) c = DEPTH;
      if (c > 0) {
        int g = atomicAdd(&gcur[t], c);
        for (int k = 0; k < c; ++k) binned[g + k] = buf[t][k];
      }
    }
    __syncthreads();
  }
}

// ---------------- fused per-bucket: deg hist + local scan + place + rowstart -----
// Bucket b's nodes occupy csr[bstart[b]..bstart[b+1]) contiguously, so
// rowstart[d] = bstart[b] + local_exclusive_scan(deg). One pass over binned.
__global__ __launch_bounds__(256) void k_build(const unsigned* __restrict__ binned,
                                               const int* __restrict__ bstart, int N,
                                               int* __restrict__ deg,
                                               float* __restrict__ dinv,
                                               int* __restrict__ rowstart,
                                               int* __restrict__ csr) {
  __shared__ int hist[BW];
  __shared__ int loc[BW];
  __shared__ int scanbuf[256];
  int b = blockIdx.x;
  int t = threadIdx.x;
  int d0 = (int)(((long long)b * N + NB - 1) / NB);
  int d1 = (int)(((long long)(b + 1) * N + NB - 1) / NB);
  if (d1 > N) d1 = N;
  int W = d1 - d0;
  for (int w = t; w < BW; w += 256) hist[w] = 0;
  __syncthreads();
  int s = bstart[b], e = bstart[b + 1];
  // pass 1: degree histogram
  for (int i = s + t; i < e; i += 256)
    atomicAdd(&hist[binned[i] >> 17], 1);
  __syncthreads();
  // local exclusive scan over W (<= 400) entries: thread t owns elems 2t, 2t+1
  int e0 = t * 2, e1 = t * 2 + 1;
  int h0 = (e0 < W) ? hist[e0] : 0;
  int h1 = (e1 < W) ? hist[e1] : 0;
  scanbuf[t] = h0 + h1;
  __syncthreads();
  for (int off = 1; off < 256; off <<= 1) {
    int x = (t >= off) ? scanbuf[t - off] : 0;
    __syncthreads();
    scanbuf[t] += x;
    __syncthreads();
  }
  int excl = scanbuf[t] - (h0 + h1);
  if (e0 < W) loc[e0] = excl;
  if (e1 < W) loc[e1] = excl + h0;
  // write deg/dinv/rowstart, reset hist as cursors
  if (e0 < W) {
    deg[d0 + e0] = h0;
    dinv[d0 + e0] = rsqrtf((float)(h0 + 1));
    rowstart[d0 + e0] = s + loc[e0];
    hist[e0] = 0;
  }
  if (e1 < W) {
    deg[d0 + e1] = h1;
    dinv[d0 + e1] = rsqrtf((float)(h1 + 1));
    rowstart[d0 + e1] = s + loc[e1];
    hist[e1] = 0;
  }
  __syncthreads();
  // pass 2: place
  for (int i = s + t; i < e; i += 256) {
    unsigned p = binned[i];
    int dl = (int)(p >> 17);
    int sn = (int)(p & 0x1ffffu);
    int pos = s + loc[dl] + atomicAdd(&hist[dl], 1);
    csr[pos] = sn;
  }
}

// ============ MFMA GEMM, layers 2/3: Cbf16 = dinv(row)*(Abf16[N][128] @ W[128][128]) ==
__global__ __launch_bounds__(256) void k_gemm_mf(const unsigned* __restrict__ A,
                                                 const unsigned* __restrict__ Wt,
                                                 const float* __restrict__ dscale,
                                                 unsigned* __restrict__ Cu, int N) {
  int t = threadIdx.x;
  int w = t >> 6;
  int l = t & 63;
  int lr = l & 15;
  int kg = l >> 4;
  int wr0 = blockIdx.x * 128 + w * 32;

  f32x4 acc[2][8];
#pragma unroll
  for (int rt = 0; rt < 2; ++rt)
#pragma unroll
    for (int f = 0; f < 8; ++f) acc[rt][f] = (f32x4){0.f, 0.f, 0.f, 0.f};

  int r0 = wr0 + lr, r1 = wr0 + 16 + lr;
#pragma unroll
  for (int kt = 0; kt < 4; ++kt) {
    int ko = kt * 16 + kg * 4;
    bf16x8 a0 = {}, a1 = {};
    if (r0 < N) a0 = *(const bf16x8*)&A[(long)r0 * 64 + ko];
    if (r1 < N) a1 = *(const bf16x8*)&A[(long)r1 * 64 + ko];
#pragma unroll
    for (int f = 0; f < 8; ++f) {
      bf16x8 b = *(const bf16x8*)&Wt[(f * 16 + lr) * 64 + ko];
      acc[0][f] = __builtin_amdgcn_mfma_f32_16x16x32_bf16(a0, b, acc[0][f], 0, 0, 0);
      acc[1][f] = __builtin_amdgcn_mfma_f32_16x16x32_bf16(a1, b, acc[1][f], 0, 0, 0);
    }
  }
#pragma unroll
  for (int rt = 0; rt < 2; ++rt) {
#pragma unroll
    for (int reg = 0; reg < 4; ++reg) {
      int row = wr0 + rt * 16 + kg * 4 + reg;
      float ds = (row < N) ? dscale[row] : 0.f;
#pragma unroll
      for (int f = 0; f < 8; ++f) {
        float v = acc[rt][f][reg] * ds;
        float pv = __shfl_xor(v, 1);
        if (!(l & 1) && row < N)
          Cu[(long)row * 64 + ((f * 16 + lr) >> 1)] = pk2(v, pv);
      }
    }
  }
}

// ============ MFMA GEMM, layer 1: x f32 -> bf16 in-flight ============
__global__ __launch_bounds__(256) void k_gemm1_mf(const float* __restrict__ X,
                                                  const unsigned* __restrict__ Wt,
                                                  const float* __restrict__ dscale,
                                                  unsigned* __restrict__ Cu, int N, int K) {
  int t = threadIdx.x;
  int w = t >> 6;
  int l = t & 63;
  int lr = l & 15;
  int kg = l >> 4;
  int wr0 = blockIdx.x * 128 + w * 32;

  f32x4 acc[2][8];
#pragma unroll
  for (int rt = 0; rt < 2; ++rt)
#pragma unroll
    for (int f = 0; f < 8; ++f) acc[rt][f] = (f32x4){0.f, 0.f, 0.f, 0.f};

  int r0 = wr0 + lr, r1 = wr0 + 16 + lr;
  int nkt = (K + 31) / 32;  // 9 for K=260
  for (int kt = 0; kt < nkt; ++kt) {
    int kb = kt * 32 + kg * 8;
    bf16x8 a0 = {}, a1 = {};
    if (kb + 7 < K) {
      if (r0 < N) {
        const float* p = &X[(long)r0 * K + kb];
        float4 u = *(const float4*)p, v = *(const float4*)(p + 4);
        union { uint4 q; bf16x8 b; } cv;
        cv.q.x = pk2(u.x, u.y); cv.q.y = pk2(u.z, u.w);
        cv.q.z = pk2(v.x, v.y); cv.q.w = pk2(v.z, v.w);
        a0 = cv.b;
      }
      if (r1 < N) {
        const float* p = &X[(long)r1 * K + kb];
        float4 u = *(const float4*)p, v = *(const float4*)(p + 4);
        union { uint4 q; bf16x8 b; } cv;
        cv.q.x = pk2(u.x, u.y); cv.q.y = pk2(u.z, u.w);
        cv.q.z = pk2(v.x, v.y); cv.q.w = pk2(v.z, v.w);
        a1 = cv.b;
      }
    } else if (kb < K) {  // partial tail (k=256..259)
      float t0[8], t1[8];
#pragma unroll
      for (int j = 0; j < 8; ++j) {
        int k = kb + j;
        t0[j] = (r0 < N && k < K) ? X[(long)r0 * K + k] : 0.f;
        t1[j] = (r1 < N && k < K) ? X[(long)r1 * K + k] : 0.f;
      }
      union { uint4 q; bf16x8 b; } c0, c1;
      c0.q.x = pk2(t0[0], t0[1]); c0.q.y = pk2(t0[2], t0[3]);
      c0.q.z = pk2(t0[4], t0[5]); c0.q.w = pk2(t0[6], t0[7]);
      c1.q.x = pk2(t1[0], t1[1]); c1.q.y = pk2(t1[2], t1[3]);
      c1.q.z = pk2(t1[4], t1[5]); c1.q.w = pk2(t1[6], t1[7]);
      a0 = c0.b; a1 = c1.b;
    }
    int ko = kt * 16 + kg * 4;
#pragma unroll
    for (int f = 0; f < 8; ++f) {
      bf16x8 b = *(const bf16x8*)&Wt[(f * 16 + lr) * 144 + ko];
      acc[0][f] = __builtin_amdgcn_mfma_f32_16x16x32_bf16(a0, b, acc[0][f], 0, 0, 0);
      acc[1][f] = __builtin_amdgcn_mfma_f32_16x16x32_bf16(a1, b, acc[1][f], 0, 0, 0);
    }
  }
#pragma unroll
  for (int rt = 0; rt < 2; ++rt) {
#pragma unroll
    for (int reg = 0; reg < 4; ++reg) {
      int row = wr0 + rt * 16 + kg * 4 + reg;
      float ds = (row < N) ? dscale[row] : 0.f;
#pragma unroll
      for (int f = 0; f < 8; ++f) {
        float v = acc[rt][f][reg] * ds;
        float pv = __shfl_xor(v, 1);
        if (!(l & 1) && row < N)
          Cu[(long)row * 64 + ((f * 16 + lr) >> 1)] = pk2(v, pv);
      }
    }
  }
}

// ---------------- pull aggregation v4: 16 lanes x uint4 per node ----------------
__global__ __launch_bounds__(256) void k_agg(const uint4* __restrict__ T4,  // [N][16]
                                             const float* __restrict__ dinv,
                                             const int* __restrict__ rowstart,
                                             const int* __restrict__ deg,
                                             const int* __restrict__ csr,
                                             const float* __restrict__ bias,
                                             uint4* __restrict__ outu,      // [N][16]
                                             int N) {
  int t = threadIdx.x;
  int grp = t >> 4;        // node slot 0..15
  int lane = t & 15;       // uint4 slot in row (8 channels)
  int i = blockIdx.x * 16 + grp;
  if (i >= N) return;

  int c0 = lane * 8;
  float b0 = bias[c0 + 0], b1 = bias[c0 + 1], b2 = bias[c0 + 2], b3 = bias[c0 + 3];
  float b4 = bias[c0 + 4], b5 = bias[c0 + 5], b6 = bias[c0 + 6], b7 = bias[c0 + 7];

  uint4 su = T4[(long)i * 16 + lane];  // self-loop (pre-scaled)
  float a0 = blo(su.x), a1 = bhi(su.x), a2 = blo(su.y), a3 = bhi(su.y);
  float a4 = blo(su.z), a5 = bhi(su.z), a6 = blo(su.w), a7 = bhi(su.w);

  int s0 = rowstart[i];
  int d = deg[i];
  int j = 0;
  for (; j + 3 < d; j += 4) {
    int n1 = csr[s0 + j];
    int n2 = csr[s0 + j + 1];
    int n3 = csr[s0 + j + 2];
    int n4 = csr[s0 + j + 3];
    uint4 u1 = T4[(long)n1 * 16 + lane];
    uint4 u2 = T4[(long)n2 * 16 + lane];
    uint4 u3 = T4[(long)n3 * 16 + lane];
    uint4 u4 = T4[(long)n4 * 16 + lane];
    a0 += (blo(u1.x) + blo(u2.x)) + (blo(u3.x) + blo(u4.x));
    a1 += (bhi(u1.x) + bhi(u2.x)) + (bhi(u3.x) + bhi(u4.x));
    a2 += (blo(u1.y) + blo(u2.y)) + (blo(u3.y) + blo(u4.y));
    a3 += (bhi(u1.y) + bhi(u2.y)) + (bhi(u3.y) + bhi(u4.y));
    a4 += (blo(u1.z) + blo(u2.z)) + (blo(u3.z) + blo(u4.z));
    a5 += (bhi(u1.z) + bhi(u2.z)) + (bhi(u3.z) + bhi(u4.z));
    a6 += (blo(u1.w) + blo(u2.w)) + (blo(u3.w) + blo(u4.w));
    a7 += (bhi(u1.w) + bhi(u2.w)) + (bhi(u3.w) + bhi(u4.w));
  }
  for (; j < d; ++j) {
    int n1 = csr[s0 + j];
    uint4 u1 = T4[(long)n1 * 16 + lane];
    a0 += blo(u1.x); a1 += bhi(u1.x); a2 += blo(u1.y); a3 += bhi(u1.y);
    a4 += blo(u1.z); a5 += bhi(u1.z); a6 += blo(u1.w); a7 += bhi(u1.w);
  }
  float di = dinv[i];
  float v0 = fmaxf(di * a0 + b0, 0.f);
  float v1 = fmaxf(di * a1 + b1, 0.f);
  float v2 = fmaxf(di * a2 + b2, 0.f);
  float v3 = fmaxf(di * a3 + b3, 0.f);
  float v4 = fmaxf(di * a4 + b4, 0.f);
  float v5 = fmaxf(di * a5 + b5, 0.f);
  float v6 = fmaxf(di * a6 + b6, 0.f);
  float v7 = fmaxf(di * a7 + b7, 0.f);
  uint4 o;
  o.x = pk2(v0, v1); o.y = pk2(v2, v3); o.z = pk2(v4, v5); o.w = pk2(v6, v7);
  outu[(long)i * 16 + lane] = o;
}

// ---------------- graph start offsets from sorted batch ----------------
__global__ void k_starts(const int* __restrict__ batch, int N, int* __restrict__ start) {
  int i = blockIdx.x * blockDim.x + threadIdx.x;
  int stride = gridDim.x * blockDim.x;
  for (; i < N; i += stride) {
    int g = batch[i];
    if (i == 0) {
      start[g] = 0;
    } else if (batch[i - 1] != g) {
      start[g] = i;
    }
  }
}

// parallel back-fill of empty graphs via reverse min-scan (starts monotone)
__global__ __launch_bounds__(256) void k_fix_starts(int* __restrict__ start, int G, int N) {
  __shared__ int sh[256];
  int t = threadIdx.x;
  int v = (t < G) ? start[t] : N;
  if (v < 0) v = N;
  sh[t] = v;
  __syncthreads();
  for (int off = 1; off < 256; off <<= 1) {
    int x = (t + off < 256) ? sh[t + off] : N;
    int nv = min(sh[t], x);
    __syncthreads();
    sh[t] = nv;
    __syncthreads();
  }
  if (t < G) start[t] = sh[t];
  if (t == 0) start[G] = N;
}

// ---------------- parallel mean-pool (batch sorted, h bf16 [N][64]) -------------
__global__ __launch_bounds__(256) void k_pool2(const unsigned* __restrict__ hu,
                                               const int* __restrict__ batch,
                                               float* __restrict__ psum, int N) {
  int t = threadIdx.x;
  int rg = t >> 6;        // row group 0..3
  int lane = t & 63;      // u32 index in row
  long base = (long)blockIdx.x * 64;
  float a0 = 0.f, a1 = 0.f;
  int cur = -1;
#pragma unroll
  for (int j = 0; j < 16; ++j) {
    long r = base + j * 4 + rg;
    if (r >= N) break;
    int g = batch[r];
    if (g != cur) {
      if (cur >= 0) {
        atomicAdd(&psum[cur * HID + lane * 2], a0);
        atomicAdd(&psum[cur * HID + lane * 2 + 1], a1);
        a0 = 0.f; a1 = 0.f;
      }
      cur = g;
    }
    unsigned u = hu[r * 64 + lane];
    a0 += blo(u); a1 += bhi(u);
  }
  if (cur >= 0) {
    atomicAdd(&psum[cur * HID + lane * 2], a0);
    atomicAdd(&psum[cur * HID + lane * 2 + 1], a1);
  }
}

// ---------------- MLP head ----------------
__global__ __launch_bounds__(128) void k_head(const float* __restrict__ psum,
                                              const int* __restrict__ gstart,
                                              const float* __restrict__ fc1w,
                                              const float* __restrict__ fc1b,
                                              const float* __restrict__ fc2w,
                                              const float* __restrict__ fc2b,
                                              float* __restrict__ out, int G) {
  __shared__ float pooled[HID];
  __shared__ float z1[HID];
  int g = blockIdx.x;
  int c = threadIdx.x;
  float cn = fmaxf((float)(gstart[g + 1] - gstart[g]), 1.f);
  pooled[c] = psum[g * HID + c] / cn;
  __syncthreads();
  float a = fc1b[c];
#pragma unroll 8
  for (int k = 0; k < HID; ++k) a += pooled[k] * fc1w[k * HID + c];
  z1[c] = fmaxf(a, 0.f);
  __syncthreads();
  if (c < 16) {
    float o = fc2b[c];
#pragma unroll 8
    for (int k = 0; k < HID; ++k) o += z1[k] * fc2w[k * 16 + c];
    out[g * 16 + c] = o;
  }
}

extern "C" void kernel_launch(void* const* d_in, const int* in_sizes, int n_in,
                              void* d_out, int out_size, void* d_ws, size_t ws_size,
                              hipStream_t stream) {
  const float* x     = (const float*)d_in[0];
  const int*   ei    = (const int*)d_in[1];
  const int*   batch = (const int*)d_in[2];
  const float* w1    = (const float*)d_in[3];
  const float* b1    = (const float*)d_in[4];
  const float* w2    = (const float*)d_in[5];
  const float* b2    = (const float*)d_in[6];
  const float* w3    = (const float*)d_in[7];
  const float* b3    = (const float*)d_in[8];
  const float* fc1w  = (const float*)d_in[9];
  const float* fc1b  = (const float*)d_in[10];
  const float* fc2w  = (const float*)d_in[11];
  const float* fc2b  = (const float*)d_in[12];
  float* out = (float*)d_out;

  const int IN = in_sizes[3] / HID;   // 260
  const int N  = in_sizes[0] / IN;    // 100000
  const int E  = in_sizes[1] / 2;     // 3200000
  const int G  = out_size / 16;       // 64

  const int* srcp = ei;
  const int* dstp = ei + E;

  // ---- workspace carve ----
  char* wsp = (char*)d_ws;
  auto alloc = [&](size_t bytes) {
    char* p = wsp;
    wsp += (bytes + 255) & ~(size_t)255;
    return p;
  };
  int*   deg      = (int*)alloc((size_t)N * 4);
  int*   rowstart = (int*)alloc((size_t)N * 4);
  int*   bhist    = (int*)alloc(NB * 4);
  int*   bstart   = (int*)alloc((NB + 1) * 4);
  int*   gcur     = (int*)alloc(NB * 4);
  int*   gstart   = (int*)alloc((size_t)(G + 1) * 4);
  float* dinv     = (float*)alloc((size_t)N * 4);
  float* psum     = (float*)alloc((size_t)G * HID * 4);
  unsigned* Wt1   = (unsigned*)alloc(128 * 144 * 4);
  unsigned* Wt2   = (unsigned*)alloc(128 * 64 * 4);
  unsigned* Wt3   = (unsigned*)alloc(128 * 64 * 4);
  int*   csr      = (int*)alloc((size_t)E * 4);
  unsigned* bufA  = (unsigned*)alloc((size_t)N * 64 * 4);  // bf16 [N][128] packed
  unsigned* bufB  = (unsigned*)alloc((size_t)N * 64 * 4);  // bf16 [N][128] packed
  // binned edge array (E x 4B = 12.8MB) aliases bufA; consumed before first GEMM.
  unsigned* binned = (unsigned*)bufA;

  // ---- fused prep (weights + init) ----
  k_prep_init<<<136, 256, 0, stream>>>(w1, w2, w3, Wt1, Wt2, Wt3,
                                       psum, gstart, bhist, IN, G);

  // ---- binned CSR build (u32-packed, fused build) ----
  k_hist<<<512, 256, 0, stream>>>(dstp, E, N, bhist);
  k_bscan<<<1, NB, 0, stream>>>(bhist, bstart, gcur, E);
  k_scatter<<<782, 256, 0, stream>>>(srcp, dstp, E, N, binned, gcur);
  k_build<<<NB, 256, 0, stream>>>(binned, bstart, N, deg, dinv, rowstart, csr);

  // ---- graph boundaries ----
  k_starts<<<256, 256, 0, stream>>>(batch, N, gstart);
  k_fix_starts<<<1, 256, 0, stream>>>(gstart, G, N);

  // ---- 3 GCN layers: MFMA GEMM (epilogue scales by dinv, packs bf16) + agg ----
  int gblocks = (N + 127) / 128;
  int ablocks = (N + 15) / 16;
  k_gemm1_mf<<<gblocks, 256, 0, stream>>>(x, Wt1, dinv, bufA, N, IN);
  k_agg<<<ablocks, 256, 0, stream>>>((const uint4*)bufA, dinv, rowstart, deg, csr, b1,
                                     (uint4*)bufB, N);

  k_gemm_mf<<<gblocks, 256, 0, stream>>>(bufB, Wt2, dinv, bufA, N);
  k_agg<<<ablocks, 256, 0, stream>>>((const uint4*)bufA, dinv, rowstart, deg, csr, b2,
                                     (uint4*)bufB, N);

  k_gemm_mf<<<gblocks, 256, 0, stream>>>(bufB, Wt3, dinv, bufA, N);
  k_agg<<<ablocks, 256, 0, stream>>>((const uint4*)bufA, dinv, rowstart, deg, csr, b3,
                                     (uint4*)bufB, N);

  // ---- pool + head ----
  int pblocks = (N + 63) / 64;
  k_pool2<<<pblocks, 256, 0, stream>>>(bufB, batch, psum, N);
  k_head<<<G, 128, 0, stream>>>(psum, gstart, fc1w, fc1b, fc2w, fc2b, out, G);
}